// Round 7
// baseline (9489.986 us; speedup 1.0000x reference)
//
#include <hip/hip_runtime.h>
#include <hip/hip_bf16.h>

// Hypernetwork RNN scan. B=16, N=2048, M=H=64, L*E=1024, Cout=256.
// Round 7: poison-mailbox exchange. R5/R6 regressed because 24 lanes/WG of
// agent-scope u64 atomic polls on reused parity slots saturated the LLC
// atomic path (R4's 1-lane poll beat both). Now the bf16 m-history buffer
// IS the mailbox: producers store 4 packed u64s at a monotonically
// advancing address (no reuse -> no tags); a word is valid iff != 0xAA..
// poison (sigmoid bf16 has sign bit 0, so poison is unreachable). Consumer
// polls with ONE coalesced 128-B sc1 load (lanes 0-15) -- detection IS the
// payload: single RTT, one instruction per poll. Mailbox memset to 0xAA in
// kernel_launch (graph-capture-safe). P stored bf16 to fund the mailbox.
//   K1 cvt: Wd->bf16 slice layout; dec_w->bf16 lane-packed; enc m-rows->EWmG
//   K2 build_T (f32, 8 MB), K3 build_P -> bf16 P (8 MB)
//   K4 recur: 64 WGs = 16 batches x 4 i-slices; Wd in VGPRs
//   K5 loss:  parallel logits/LSE/NLL over the bf16 m mailbox

typedef unsigned int uint_t;
typedef unsigned short us_t;
typedef unsigned long long u64_t;

#define POISON64 0xAAAAAAAAAAAAAAAAULL

__device__ __forceinline__ us_t f2bf(float f) {
    uint_t u = __float_as_uint(f);
    uint_t r = u + 0x7fffu + ((u >> 16) & 1u);   // RNE
    return (us_t)(r >> 16);
}
__device__ __forceinline__ float bf2f(us_t s) {
    return __uint_as_float(((uint_t)s) << 16);
}
__device__ __forceinline__ float bflo(uint_t u) { return __uint_as_float(u << 16); }
__device__ __forceinline__ float bfhi(uint_t u) { return __uint_as_float(u & 0xffff0000u); }

#define MAC8(q, acc)                                                    \
    acc += bflo(q.x) * mreg[0] + bfhi(q.x) * mreg[1]                    \
         + bflo(q.y) * mreg[2] + bfhi(q.y) * mreg[3]                    \
         + bflo(q.z) * mreg[4] + bfhi(q.z) * mreg[5]                    \
         + bflo(q.w) * mreg[6] + bfhi(q.w) * mreg[7];

#define LOADM8(jp)                                                      \
    float4 _ml = m4[(jp) * 2], _mh = m4[(jp) * 2 + 1];                  \
    float mreg[8] = {_ml.x, _ml.y, _ml.z, _ml.w, _mh.x, _mh.y, _mh.z, _mh.w};

// ---------------- K1: convert/swizzle weights ----------------
// WdG  [s<4][jp<8][o<1024][k<8], o=h*16+il, val = Wd[h][(s*16+il)*64+jp*8+k]
// decwY [mm<64][lane<64][k<4],   val = decw[mm*256 + k*64 + lane]
// EWmG [jp<8][h2<128][k<8],      val = enc_m_row(j=jp*8+k, h2)
__global__ void cvt_kernel(const float* __restrict__ Wdecw,
                           const float* __restrict__ decw,
                           const float* __restrict__ Wencw,
                           const float* __restrict__ bencw,
                           us_t* __restrict__ WdG, us_t* __restrict__ decwY,
                           us_t* __restrict__ EWmG) {
    int o = blockIdx.x * 256 + threadIdx.x;
    if (o < 262144) {
        int s = o >> 16;
        int idx = o & 65535;
        int k = idx & 7;
        int oo = (idx >> 3) & 1023;
        int jp = idx >> 13;
        int h = oo >> 4, il = oo & 15;
        int i = s * 16 + il;
        int j = jp * 8 + k;
        WdG[o] = f2bf(Wdecw[h * 4096 + i * 64 + j]);
    } else if (o < 278528) {
        int oo = o - 262144;
        int k = oo & 3, lane = (oo >> 2) & 63, mm = oo >> 8;
        decwY[oo] = f2bf(decw[mm * 256 + k * 64 + lane]);
    } else if (o < 286720) {
        int oo = o - 278528;
        int kk = oo & 7, h2 = (oo >> 3) & 127, jp = oo >> 10;
        int j = jp * 8 + kk;
        float v = (h2 < 64) ? Wencw[j * 64 + h2] : bencw[j * 64 + (h2 - 64)];
        EWmG[oo] = f2bf(v);
    }
}

// ---------------- K2: token contribution table ----------------
__global__ void build_T(const float* __restrict__ emb, const float* __restrict__ Wencw,
                        const float* __restrict__ bencw, float* __restrict__ T) {
    int l = blockIdx.x >> 8, v = blockIdx.x & 255, h2 = threadIdx.x;  // h2 < 128
    float acc = 0.f;
#pragma unroll
    for (int e = 0; e < 16; ++e) {
        int d = 64 + l * 16 + e;
        float w = (h2 < 64) ? Wencw[d * 64 + h2] : bencw[d * 64 + (h2 - 64)];
        acc += emb[v * 16 + e] * w;
    }
    T[blockIdx.x * 128 + h2] = acc;
}

// ---------------- K3: window precompute P (bf16 out) ----------------
__global__ void build_P(const float* __restrict__ T, const int* __restrict__ x0,
                        const float* __restrict__ Wencb, const float* __restrict__ bencb,
                        us_t* __restrict__ Pb) {
    int t = blockIdx.x >> 4, b = blockIdx.x & 15, h2 = threadIdx.x;  // h2 < 128
    float acc = (h2 < 64) ? Wencb[h2] : bencb[h2 - 64];
    for (int l = 0; l < 64; ++l) {
        int p = t + l;
        int v = (p < 64) ? 0 : x0[b * 2048 + (p - 64)];
        acc += T[(l * 256 + v) * 128 + h2];
    }
    Pb[blockIdx.x * 128 + h2] = f2bf(acc);
}

// ---------------- K4: sequential recurrence ----------------
// grid 64: b = blk&15, s = blk>>4. ~10 KB static LDS; Wd in VGPRs.
__global__ __launch_bounds__(512, 2) void recur(
    const float* __restrict__ bdecw, const float* __restrict__ bdecb,
    const float* __restrict__ Wdecb, const us_t* __restrict__ WdG,
    const us_t* __restrict__ EWmG, const us_t* __restrict__ Pb,
    u64_t* __restrict__ mhb) {
    const int b = blockIdx.x & 15, s = blockIdx.x >> 4;
    const int tid = threadIdx.x;

    __shared__ us_t  wdbt_s[64 * 17];             // [j][il]  W_dec_b[i*64+j]
    __shared__ us_t  bdec_s[64 * 17];             // [h][il]  b_dec_w[h][i]
    __shared__ float hw_s[64], hb_s[64];
    __shared__ __align__(16) float m_s[64];
    __shared__ float V_s[64 * 17];                // [h][il] stride-17
    __shared__ float rp_s[128];                   // [p<8][il]
    __shared__ float bias_s[16];

    // ---- init: Wd slice -> registers (rows o=tid and o=tid+512) ----
    uint4 wreg[16];
    {
        const uint4* g4 = (const uint4*)WdG + s * 8192;
#pragma unroll
        for (int jp = 0; jp < 8; ++jp) {
            wreg[jp]     = g4[jp * 1024 + tid];
            wreg[8 + jp] = g4[jp * 1024 + tid + 512];
        }
    }
    // encoder m-rows -> registers (henc threads only), straight from global
    uint4 ereg[8];
    if (tid < 128) {
        const uint4* e4 = (const uint4*)EWmG;
#pragma unroll
        for (int jp = 0; jp < 8; ++jp) ereg[jp] = e4[jp * 128 + tid];
    }
    for (int k = tid; k < 1024; k += 512) {
        int j = k >> 4, il = k & 15;
        wdbt_s[j * 17 + il] = f2bf(Wdecb[(s * 16 + il) * 64 + j]);
        bdec_s[j * 17 + il] = f2bf(bdecw[j * 64 + s * 16 + il]);
    }
    if (tid < 16) bias_s[tid] = bdecb[s * 16 + tid];
    if (tid < 64) m_s[tid] = 0.f;
    __syncthreads();

    float preg = 0.f;
    if (tid < 128) preg = bf2f(Pb[b * 128 + tid]);  // t = 0

    const int hA = tid >> 4, ilA = tid & 15;
    const float4* m4 = (const float4*)m_s;

    for (int t = 0; t < 2048; ++t) {
        // ---- phase A: prefetch P(t+1); V slice from wreg; henc from ereg ----
        float pnext = 0.f;
        int tp = (t < 2047) ? (t + 1) : 2047;
        if (tid < 128) pnext = bf2f(Pb[(tp * 16 + b) * 128 + tid]);

        float a0 = 0.f, a1 = 0.f;
        if (tid < 128) {
            float ae = preg;
#pragma unroll
            for (int jp = 0; jp < 8; ++jp) {
                LOADM8(jp);
                uint4 q0 = wreg[jp], q1 = wreg[8 + jp], e = ereg[jp];
                MAC8(q0, a0);
                MAC8(q1, a1);
                MAC8(e, ae);
            }
            float sg = 1.f / (1.f + __expf(-ae));
            if (tid < 64) hw_s[tid] = sg; else hb_s[tid - 64] = sg;
        } else {
#pragma unroll
            for (int jp = 0; jp < 8; ++jp) {
                LOADM8(jp);
                uint4 q0 = wreg[jp], q1 = wreg[8 + jp];
                MAC8(q0, a0);
                MAC8(q1, a1);
            }
        }
        V_s[hA * 17 + ilA] = a0;
        V_s[(hA + 32) * 17 + ilA] = a1;
        preg = pnext;
        __syncthreads();

        // ---- phase B: r partials on 128 threads ----
        if (tid < 128) {
            int il = tid & 15, q = (tid >> 4) & 3;
            if (tid < 64) {
                float r = 0.f;
#pragma unroll
                for (int hh = 0; hh < 16; ++hh) {
                    int h = q * 16 + hh;
                    r += hw_s[h] * V_s[h * 17 + il];
                }
                rp_s[q * 16 + il] = r;
            } else {
                float r = 0.f;
#pragma unroll
                for (int kk = 0; kk < 16; ++kk) {
                    int jh = q * 16 + kk;
                    r += m_s[jh] * bf2f(wdbt_s[jh * 17 + il]);
                    r += hb_s[jh] * bf2f(bdec_s[jh * 17 + il]);
                }
                rp_s[64 + q * 16 + il] = r;
            }
        }
        __syncthreads();

        // ---- phase C + mailbox exchange (wave 0 only) ----
        if (tid < 64) {
            u64_t* row = mhb + (u64_t)(t * 16 + b) * 16;  // 16 u64 = 64 bf16
            float nmf = 0.f;
            if (tid < 16) {
                float r = bias_s[tid];
#pragma unroll
                for (int p = 0; p < 8; ++p) r += rp_s[p * 16 + tid];
                nmf = 1.f / (1.f + __expf(-r));
            }
            us_t nb = f2bf(nmf);                 // bf16-round: all WGs agree
            if (tid < 16) m_s[s * 16 + tid] = bf2f(nb);   // own slice, local
            // shfl-pack: lane j<4 gathers lanes 4j..4j+3 into one u64
            uint_t nbu = (uint_t)nb;
            uint_t w0 = (uint_t)__shfl((int)nbu, (tid & 3) * 4 + 0, 64);
            uint_t w1 = (uint_t)__shfl((int)nbu, (tid & 3) * 4 + 1, 64);
            uint_t w2 = (uint_t)__shfl((int)nbu, (tid & 3) * 4 + 2, 64);
            uint_t w3 = (uint_t)__shfl((int)nbu, (tid & 3) * 4 + 3, 64);
            if (tid < 4) {
                u64_t pay = (u64_t)w0 | ((u64_t)w1 << 16)
                          | ((u64_t)w2 << 32) | ((u64_t)w3 << 48);
                __hip_atomic_store(row + s * 4 + tid, pay,
                                   __ATOMIC_RELAXED, __HIP_MEMORY_SCOPE_AGENT);
            }
            // poll: lanes 0..15 load the whole row (one coalesced 128-B sc1
            // op). A word is valid iff != poison; own words always "ok".
            const bool self = (tid >> 2) == s;
            u64_t vk = 0;
            for (;;) {
                if (tid < 16 && !self)
                    vk = __hip_atomic_load(row + tid, __ATOMIC_RELAXED,
                                           __HIP_MEMORY_SCOPE_AGENT);
                bool ok = (tid >= 16) || self || (vk != POISON64);
                if (__ballot(ok) == ~0ull) break;
                __builtin_amdgcn_s_sleep(1);
            }
            if (tid < 16 && !self) {
                float4 mv;
                mv.x = bf2f((us_t)(vk & 0xFFFFu));
                mv.y = bf2f((us_t)((vk >> 16) & 0xFFFFu));
                mv.z = bf2f((us_t)((vk >> 32) & 0xFFFFu));
                mv.w = bf2f((us_t)(vk >> 48));
                ((float4*)m_s)[tid] = mv;
            }
        }
        __syncthreads();   // wave-0 LDS writes visible; all waves reload m4
    }
}

// ---------------- K5: parallel loss (reads bf16 mailbox) ----------------
__global__ __launch_bounds__(256) void loss_kernel(
    const us_t* __restrict__ mhb, const us_t* __restrict__ decwY,
    const float* __restrict__ decb, const int* __restrict__ x0,
    float* __restrict__ out) {
    __shared__ __align__(16) us_t dw[16384];   // [mm][lane][k<4] bf16
    const int tid = threadIdx.x;
    {
        const uint4* g4 = (const uint4*)decwY;
        uint4* l4 = (uint4*)dw;
        for (int k = tid; k < 2048; k += 256) l4[k] = g4[k];
    }
    __syncthreads();
    const int lane = tid & 63, wv = tid >> 6;
    const uint2* dwu2 = (const uint2*)dw;
    float b0 = decb[lane], b1 = decb[lane + 64];
    float b2 = decb[lane + 128], b3 = decb[lane + 192];
    for (int r = 0; r < 8; ++r) {
        int row = blockIdx.x * 32 + wv * 8 + r;
        float mL = bf2f(mhb[row * 64 + lane]);
        float l0 = b0, l1 = b1, l2 = b2, l3 = b3;
#pragma unroll
        for (int mm = 0; mm < 64; ++mm) {
            float mv = __shfl(mL, mm, 64);
            uint2 q = dwu2[mm * 64 + lane];
            l0 += mv * bflo(q.x);
            l1 += mv * bfhi(q.x);
            l2 += mv * bflo(q.y);
            l3 += mv * bfhi(q.y);
        }
        float mx = fmaxf(fmaxf(l0, l1), fmaxf(l2, l3));
#pragma unroll
        for (int o = 32; o > 0; o >>= 1) mx = fmaxf(mx, __shfl_xor(mx, o, 64));
        float se = __expf(l0 - mx) + __expf(l1 - mx) + __expf(l2 - mx) + __expf(l3 - mx);
#pragma unroll
        for (int o = 32; o > 0; o >>= 1) se += __shfl_xor(se, o, 64);
        float lse = mx + __logf(se);
        int t = row >> 4, bb = row & 15;
        int y = x0[bb * 2048 + t];
        int hi = y >> 6;
        float cand = hi == 0 ? l0 : (hi == 1 ? l1 : (hi == 2 ? l2 : l3));
        float ly = __shfl(cand, y & 63, 64);
        if (lane == 0) out[row] = (lse - ly) * 1.4426950408889634f;
    }
}

extern "C" void kernel_launch(void* const* d_in, const int* in_sizes, int n_in,
                              void* d_out, int out_size, void* d_ws, size_t ws_size,
                              hipStream_t stream) {
    const int*   x0    = (const int*)d_in[0];
    const float* emb   = (const float*)d_in[1];
    const float* Wencw = (const float*)d_in[2];
    const float* Wencb = (const float*)d_in[3];
    const float* Wdecw = (const float*)d_in[4];
    const float* Wdecb = (const float*)d_in[5];
    const float* bencw = (const float*)d_in[6];
    const float* bencb = (const float*)d_in[7];
    const float* bdecw = (const float*)d_in[8];
    const float* bdecb = (const float*)d_in[9];
    const float* decw  = (const float*)d_in[10];
    const float* decb  = (const float*)d_in[11];
    float* out = (float*)d_out;

    char* ws = (char*)d_ws;
    us_t*  WdG   = (us_t*)(ws);                 //        0 .. 524288
    us_t*  decwY = (us_t*)(ws + 524288);        //   524288 .. 557056
    us_t*  EWmG  = (us_t*)(ws + 557056);        //   557056 .. 573440 (16 KB)
    u64_t* mhb   = (u64_t*)(ws + 573440);       //   573440 .. 4767744 (4 MB mailbox)
    float* T     = (float*)(ws + 4767744);      //  4767744 .. 13156352 (8 MB)
    us_t*  Pb    = (us_t*)(ws + 13156352);      // 13156352 .. 21544960 (8 MB)

    // poison the mailbox ourselves: do not rely on harness ws-poisoning
    hipMemsetAsync(mhb, 0xAA, 4194304, stream);
    cvt_kernel<<<1120, 256, 0, stream>>>(Wdecw, decw, Wencw, bencw,
                                         WdG, decwY, EWmG);
    build_T<<<16384, 128, 0, stream>>>(emb, Wencw, bencw, T);
    build_P<<<32768, 128, 0, stream>>>(T, x0, Wencb, bencb, Pb);
    recur<<<64, 512, 0, stream>>>(bdecw, bdecb, Wdecb, WdG, EWmG, Pb, mhb);
    loss_kernel<<<1024, 256, 0, stream>>>((const us_t*)mhb, decwY, decb, x0, out);
}

// Round 8
// 9474.688 us; speedup vs baseline: 1.0016x; 1.0016x over previous
//
#include <hip/hip_runtime.h>
#include <hip/hip_bf16.h>

// Hypernetwork RNN scan. B=16, N=2048, M=H=64, L*E=1024, Cout=256.
// Round 8: ONE change vs R7 — force 1 WG/CU via a 96 KB dynamic-LDS pad.
// Diagnosis: R5-R7 (small LDS, 128 VGPR) allowed the dispatcher to pack
// 2 WGs/CU; paired WGs time-slice the SIMDs and the per-step 4-way barrier
// couples every batch to the slowest pair. R4 was "fast" only because its
// 157 KB LDS forced 1 WG/CU. Static(~10K)+dynamic(96K) = ~106 KB > 160/2.
//   K1 cvt: Wd->bf16 slice layout; dec_w->bf16 lane-packed; enc m-rows->EWmG
//   K2 build_T (f32, 8 MB), K3 build_P -> bf16 P (8 MB)
//   K4 recur: 64 WGs = 16 batches x 4 i-slices; Wd in VGPRs; poison-mailbox
//             single-RTT exchange (detection IS the payload)
//   K5 loss:  parallel logits/LSE/NLL over the bf16 m mailbox

typedef unsigned int uint_t;
typedef unsigned short us_t;
typedef unsigned long long u64_t;

#define POISON64 0xAAAAAAAAAAAAAAAAULL

__device__ __forceinline__ us_t f2bf(float f) {
    uint_t u = __float_as_uint(f);
    uint_t r = u + 0x7fffu + ((u >> 16) & 1u);   // RNE
    return (us_t)(r >> 16);
}
__device__ __forceinline__ float bf2f(us_t s) {
    return __uint_as_float(((uint_t)s) << 16);
}
__device__ __forceinline__ float bflo(uint_t u) { return __uint_as_float(u << 16); }
__device__ __forceinline__ float bfhi(uint_t u) { return __uint_as_float(u & 0xffff0000u); }

#define MAC8(q, acc)                                                    \
    acc += bflo(q.x) * mreg[0] + bfhi(q.x) * mreg[1]                    \
         + bflo(q.y) * mreg[2] + bfhi(q.y) * mreg[3]                    \
         + bflo(q.z) * mreg[4] + bfhi(q.z) * mreg[5]                    \
         + bflo(q.w) * mreg[6] + bfhi(q.w) * mreg[7];

#define LOADM8(jp)                                                      \
    float4 _ml = m4[(jp) * 2], _mh = m4[(jp) * 2 + 1];                  \
    float mreg[8] = {_ml.x, _ml.y, _ml.z, _ml.w, _mh.x, _mh.y, _mh.z, _mh.w};

// ---------------- K1: convert/swizzle weights ----------------
// WdG  [s<4][jp<8][o<1024][k<8], o=h*16+il, val = Wd[h][(s*16+il)*64+jp*8+k]
// decwY [mm<64][lane<64][k<4],   val = decw[mm*256 + k*64 + lane]
// EWmG [jp<8][h2<128][k<8],      val = enc_m_row(j=jp*8+k, h2)
__global__ void cvt_kernel(const float* __restrict__ Wdecw,
                           const float* __restrict__ decw,
                           const float* __restrict__ Wencw,
                           const float* __restrict__ bencw,
                           us_t* __restrict__ WdG, us_t* __restrict__ decwY,
                           us_t* __restrict__ EWmG) {
    int o = blockIdx.x * 256 + threadIdx.x;
    if (o < 262144) {
        int s = o >> 16;
        int idx = o & 65535;
        int k = idx & 7;
        int oo = (idx >> 3) & 1023;
        int jp = idx >> 13;
        int h = oo >> 4, il = oo & 15;
        int i = s * 16 + il;
        int j = jp * 8 + k;
        WdG[o] = f2bf(Wdecw[h * 4096 + i * 64 + j]);
    } else if (o < 278528) {
        int oo = o - 262144;
        int k = oo & 3, lane = (oo >> 2) & 63, mm = oo >> 8;
        decwY[oo] = f2bf(decw[mm * 256 + k * 64 + lane]);
    } else if (o < 286720) {
        int oo = o - 278528;
        int kk = oo & 7, h2 = (oo >> 3) & 127, jp = oo >> 10;
        int j = jp * 8 + kk;
        float v = (h2 < 64) ? Wencw[j * 64 + h2] : bencw[j * 64 + (h2 - 64)];
        EWmG[oo] = f2bf(v);
    }
}

// ---------------- K2: token contribution table ----------------
__global__ void build_T(const float* __restrict__ emb, const float* __restrict__ Wencw,
                        const float* __restrict__ bencw, float* __restrict__ T) {
    int l = blockIdx.x >> 8, v = blockIdx.x & 255, h2 = threadIdx.x;  // h2 < 128
    float acc = 0.f;
#pragma unroll
    for (int e = 0; e < 16; ++e) {
        int d = 64 + l * 16 + e;
        float w = (h2 < 64) ? Wencw[d * 64 + h2] : bencw[d * 64 + (h2 - 64)];
        acc += emb[v * 16 + e] * w;
    }
    T[blockIdx.x * 128 + h2] = acc;
}

// ---------------- K3: window precompute P (bf16 out) ----------------
__global__ void build_P(const float* __restrict__ T, const int* __restrict__ x0,
                        const float* __restrict__ Wencb, const float* __restrict__ bencb,
                        us_t* __restrict__ Pb) {
    int t = blockIdx.x >> 4, b = blockIdx.x & 15, h2 = threadIdx.x;  // h2 < 128
    float acc = (h2 < 64) ? Wencb[h2] : bencb[h2 - 64];
    for (int l = 0; l < 64; ++l) {
        int p = t + l;
        int v = (p < 64) ? 0 : x0[b * 2048 + (p - 64)];
        acc += T[(l * 256 + v) * 128 + h2];
    }
    Pb[blockIdx.x * 128 + h2] = f2bf(acc);
}

// ---------------- K4: sequential recurrence ----------------
// grid 64: b = blk&15, s = blk>>4. Static ~10 KB + 96 KB dynamic pad
// => ~106 KB/WG => at most 1 WG/CU (the whole point of Round 8).
__global__ __launch_bounds__(512, 2) void recur(
    const float* __restrict__ bdecw, const float* __restrict__ bdecb,
    const float* __restrict__ Wdecb, const us_t* __restrict__ WdG,
    const us_t* __restrict__ EWmG, const us_t* __restrict__ Pb,
    u64_t* __restrict__ mhb) {
    const int b = blockIdx.x & 15, s = blockIdx.x >> 4;
    const int tid = threadIdx.x;

    extern __shared__ char occupancy_pad[];   // 96 KB requested at launch;
    if (tid == 0xFFFFF) occupancy_pad[0] = 0; // never executes; keeps it live

    __shared__ us_t  wdbt_s[64 * 17];             // [j][il]  W_dec_b[i*64+j]
    __shared__ us_t  bdec_s[64 * 17];             // [h][il]  b_dec_w[h][i]
    __shared__ float hw_s[64], hb_s[64];
    __shared__ __align__(16) float m_s[64];
    __shared__ float V_s[64 * 17];                // [h][il] stride-17
    __shared__ float rp_s[128];                   // [p<8][il]
    __shared__ float bias_s[16];

    // ---- init: Wd slice -> registers (rows o=tid and o=tid+512) ----
    uint4 wreg[16];
    {
        const uint4* g4 = (const uint4*)WdG + s * 8192;
#pragma unroll
        for (int jp = 0; jp < 8; ++jp) {
            wreg[jp]     = g4[jp * 1024 + tid];
            wreg[8 + jp] = g4[jp * 1024 + tid + 512];
        }
    }
    // encoder m-rows -> registers (henc threads only), straight from global
    uint4 ereg[8];
    if (tid < 128) {
        const uint4* e4 = (const uint4*)EWmG;
#pragma unroll
        for (int jp = 0; jp < 8; ++jp) ereg[jp] = e4[jp * 128 + tid];
    }
    for (int k = tid; k < 1024; k += 512) {
        int j = k >> 4, il = k & 15;
        wdbt_s[j * 17 + il] = f2bf(Wdecb[(s * 16 + il) * 64 + j]);
        bdec_s[j * 17 + il] = f2bf(bdecw[j * 64 + s * 16 + il]);
    }
    if (tid < 16) bias_s[tid] = bdecb[s * 16 + tid];
    if (tid < 64) m_s[tid] = 0.f;
    __syncthreads();

    float preg = 0.f;
    if (tid < 128) preg = bf2f(Pb[b * 128 + tid]);  // t = 0

    const int hA = tid >> 4, ilA = tid & 15;
    const float4* m4 = (const float4*)m_s;

    for (int t = 0; t < 2048; ++t) {
        // ---- phase A: prefetch P(t+1); V slice from wreg; henc from ereg ----
        float pnext = 0.f;
        int tp = (t < 2047) ? (t + 1) : 2047;
        if (tid < 128) pnext = bf2f(Pb[(tp * 16 + b) * 128 + tid]);

        float a0 = 0.f, a1 = 0.f;
        if (tid < 128) {
            float ae = preg;
#pragma unroll
            for (int jp = 0; jp < 8; ++jp) {
                LOADM8(jp);
                uint4 q0 = wreg[jp], q1 = wreg[8 + jp], e = ereg[jp];
                MAC8(q0, a0);
                MAC8(q1, a1);
                MAC8(e, ae);
            }
            float sg = 1.f / (1.f + __expf(-ae));
            if (tid < 64) hw_s[tid] = sg; else hb_s[tid - 64] = sg;
        } else {
#pragma unroll
            for (int jp = 0; jp < 8; ++jp) {
                LOADM8(jp);
                uint4 q0 = wreg[jp], q1 = wreg[8 + jp];
                MAC8(q0, a0);
                MAC8(q1, a1);
            }
        }
        V_s[hA * 17 + ilA] = a0;
        V_s[(hA + 32) * 17 + ilA] = a1;
        preg = pnext;
        __syncthreads();

        // ---- phase B: r partials on 128 threads ----
        if (tid < 128) {
            int il = tid & 15, q = (tid >> 4) & 3;
            if (tid < 64) {
                float r = 0.f;
#pragma unroll
                for (int hh = 0; hh < 16; ++hh) {
                    int h = q * 16 + hh;
                    r += hw_s[h] * V_s[h * 17 + il];
                }
                rp_s[q * 16 + il] = r;
            } else {
                float r = 0.f;
#pragma unroll
                for (int kk = 0; kk < 16; ++kk) {
                    int jh = q * 16 + kk;
                    r += m_s[jh] * bf2f(wdbt_s[jh * 17 + il]);
                    r += hb_s[jh] * bf2f(bdec_s[jh * 17 + il]);
                }
                rp_s[64 + q * 16 + il] = r;
            }
        }
        __syncthreads();

        // ---- phase C + mailbox exchange (wave 0 only) ----
        if (tid < 64) {
            u64_t* row = mhb + (u64_t)(t * 16 + b) * 16;  // 16 u64 = 64 bf16
            float nmf = 0.f;
            if (tid < 16) {
                float r = bias_s[tid];
#pragma unroll
                for (int p = 0; p < 8; ++p) r += rp_s[p * 16 + tid];
                nmf = 1.f / (1.f + __expf(-r));
            }
            us_t nb = f2bf(nmf);                 // bf16-round: all WGs agree
            if (tid < 16) m_s[s * 16 + tid] = bf2f(nb);   // own slice, local
            // shfl-pack: lane j<4 gathers lanes 4j..4j+3 into one u64
            uint_t nbu = (uint_t)nb;
            uint_t w0 = (uint_t)__shfl((int)nbu, (tid & 3) * 4 + 0, 64);
            uint_t w1 = (uint_t)__shfl((int)nbu, (tid & 3) * 4 + 1, 64);
            uint_t w2 = (uint_t)__shfl((int)nbu, (tid & 3) * 4 + 2, 64);
            uint_t w3 = (uint_t)__shfl((int)nbu, (tid & 3) * 4 + 3, 64);
            if (tid < 4) {
                u64_t pay = (u64_t)w0 | ((u64_t)w1 << 16)
                          | ((u64_t)w2 << 32) | ((u64_t)w3 << 48);
                __hip_atomic_store(row + s * 4 + tid, pay,
                                   __ATOMIC_RELAXED, __HIP_MEMORY_SCOPE_AGENT);
            }
            // poll: lanes 0..15 load the whole row (one coalesced 128-B sc1
            // op). A word is valid iff != poison; own words always "ok".
            const bool self = (tid >> 2) == s;
            u64_t vk = 0;
            for (;;) {
                if (tid < 16 && !self)
                    vk = __hip_atomic_load(row + tid, __ATOMIC_RELAXED,
                                           __HIP_MEMORY_SCOPE_AGENT);
                bool ok = (tid >= 16) || self || (vk != POISON64);
                if (__ballot(ok) == ~0ull) break;
                __builtin_amdgcn_s_sleep(1);
            }
            if (tid < 16 && !self) {
                float4 mv;
                mv.x = bf2f((us_t)(vk & 0xFFFFu));
                mv.y = bf2f((us_t)((vk >> 16) & 0xFFFFu));
                mv.z = bf2f((us_t)((vk >> 32) & 0xFFFFu));
                mv.w = bf2f((us_t)(vk >> 48));
                ((float4*)m_s)[tid] = mv;
            }
        }
        __syncthreads();   // wave-0 LDS writes visible; all waves reload m4
    }
}

// ---------------- K5: parallel loss (reads bf16 mailbox) ----------------
__global__ __launch_bounds__(256) void loss_kernel(
    const us_t* __restrict__ mhb, const us_t* __restrict__ decwY,
    const float* __restrict__ decb, const int* __restrict__ x0,
    float* __restrict__ out) {
    __shared__ __align__(16) us_t dw[16384];   // [mm][lane][k<4] bf16
    const int tid = threadIdx.x;
    {
        const uint4* g4 = (const uint4*)decwY;
        uint4* l4 = (uint4*)dw;
        for (int k = tid; k < 2048; k += 256) l4[k] = g4[k];
    }
    __syncthreads();
    const int lane = tid & 63, wv = tid >> 6;
    const uint2* dwu2 = (const uint2*)dw;
    float b0 = decb[lane], b1 = decb[lane + 64];
    float b2 = decb[lane + 128], b3 = decb[lane + 192];
    for (int r = 0; r < 8; ++r) {
        int row = blockIdx.x * 32 + wv * 8 + r;
        float mL = bf2f(mhb[row * 64 + lane]);
        float l0 = b0, l1 = b1, l2 = b2, l3 = b3;
#pragma unroll
        for (int mm = 0; mm < 64; ++mm) {
            float mv = __shfl(mL, mm, 64);
            uint2 q = dwu2[mm * 64 + lane];
            l0 += mv * bflo(q.x);
            l1 += mv * bfhi(q.x);
            l2 += mv * bflo(q.y);
            l3 += mv * bfhi(q.y);
        }
        float mx = fmaxf(fmaxf(l0, l1), fmaxf(l2, l3));
#pragma unroll
        for (int o = 32; o > 0; o >>= 1) mx = fmaxf(mx, __shfl_xor(mx, o, 64));
        float se = __expf(l0 - mx) + __expf(l1 - mx) + __expf(l2 - mx) + __expf(l3 - mx);
#pragma unroll
        for (int o = 32; o > 0; o >>= 1) se += __shfl_xor(se, o, 64);
        float lse = mx + __logf(se);
        int t = row >> 4, bb = row & 15;
        int y = x0[bb * 2048 + t];
        int hi = y >> 6;
        float cand = hi == 0 ? l0 : (hi == 1 ? l1 : (hi == 2 ? l2 : l3));
        float ly = __shfl(cand, y & 63, 64);
        if (lane == 0) out[row] = (lse - ly) * 1.4426950408889634f;
    }
}

extern "C" void kernel_launch(void* const* d_in, const int* in_sizes, int n_in,
                              void* d_out, int out_size, void* d_ws, size_t ws_size,
                              hipStream_t stream) {
    const int*   x0    = (const int*)d_in[0];
    const float* emb   = (const float*)d_in[1];
    const float* Wencw = (const float*)d_in[2];
    const float* Wencb = (const float*)d_in[3];
    const float* Wdecw = (const float*)d_in[4];
    const float* Wdecb = (const float*)d_in[5];
    const float* bencw = (const float*)d_in[6];
    const float* bencb = (const float*)d_in[7];
    const float* bdecw = (const float*)d_in[8];
    const float* bdecb = (const float*)d_in[9];
    const float* decw  = (const float*)d_in[10];
    const float* decb  = (const float*)d_in[11];
    float* out = (float*)d_out;

    char* ws = (char*)d_ws;
    us_t*  WdG   = (us_t*)(ws);                 //        0 .. 524288
    us_t*  decwY = (us_t*)(ws + 524288);        //   524288 .. 557056
    us_t*  EWmG  = (us_t*)(ws + 557056);        //   557056 .. 573440 (16 KB)
    u64_t* mhb   = (u64_t*)(ws + 573440);       //   573440 .. 4767744 (4 MB mailbox)
    float* T     = (float*)(ws + 4767744);      //  4767744 .. 13156352 (8 MB)
    us_t*  Pb    = (us_t*)(ws + 13156352);      // 13156352 .. 21544960 (8 MB)

    // 96 KB dynamic LDS: static(~10K)+96K ≈ 106 KB => 1 WG/CU guaranteed.
    static const int kPadLds = 98304;
    hipFuncSetAttribute((const void*)recur,
                        hipFuncAttributeMaxDynamicSharedMemorySize, kPadLds);

    // poison the mailbox ourselves: do not rely on harness ws-poisoning
    hipMemsetAsync(mhb, 0xAA, 4194304, stream);
    cvt_kernel<<<1120, 256, 0, stream>>>(Wdecw, decw, Wencw, bencw,
                                         WdG, decwY, EWmG);
    build_T<<<16384, 128, 0, stream>>>(emb, Wencw, bencw, T);
    build_P<<<32768, 128, 0, stream>>>(T, x0, Wencb, bencb, Pb);
    recur<<<64, 512, kPadLds, stream>>>(bdecw, bdecb, Wdecb, WdG, EWmG, Pb, mhb);
    loss_kernel<<<1024, 256, 0, stream>>>((const us_t*)mhb, decwY, decb, x0, out);
}

// Round 9
// 5358.295 us; speedup vs baseline: 1.7711x; 1.7682x over previous
//
#include <hip/hip_runtime.h>
#include <hip/hip_bf16.h>

// Hypernetwork RNN scan. B=16, N=2048, M=H=64, L*E=1024, Cout=256.
// Round 9: back to the measured best structure (R4, 6.58 ms) + ONE change:
// R7's single-RTT poison-mailbox exchange replaces the flag+payload barrier.
// R8 falsified the co-residency theory for the R5-R8 regression; rather than
// keep stacking changes on an unexplained baseline, this round A/B-tests the
// exchange alone on the known-good R4 body (LDS-resident Wd, persistent
// mreg[64], 128-thread phase B, 157.5 KB dynamic LDS => 1 WG/CU).
//   K1 cvt: Wd->bf16 slice layout; dec_w->bf16 lane-packed; enc m-rows->EWmG
//   K2 build_T (f32, 8 MB), K3 build_P (f32, 16 MB)
//   K4 recur: 64 WGs = 16 batches x 4 i-slices; poison-mailbox exchange
//   K5 loss:  parallel logits/LSE/NLL over the bf16 m mailbox

typedef unsigned int uint_t;
typedef unsigned short us_t;
typedef unsigned long long u64_t;

#define POISON64 0xAAAAAAAAAAAAAAAAULL

__device__ __forceinline__ us_t f2bf(float f) {
    uint_t u = __float_as_uint(f);
    uint_t r = u + 0x7fffu + ((u >> 16) & 1u);   // RNE
    return (us_t)(r >> 16);
}
__device__ __forceinline__ float bf2f(us_t s) {
    return __uint_as_float(((uint_t)s) << 16);
}
__device__ __forceinline__ float bflo(uint_t u) { return __uint_as_float(u << 16); }
__device__ __forceinline__ float bfhi(uint_t u) { return __uint_as_float(u & 0xffff0000u); }

#define MAC8(q, base, acc)                                              \
    acc += bflo(q.x) * mreg[(base) + 0] + bfhi(q.x) * mreg[(base) + 1]  \
         + bflo(q.y) * mreg[(base) + 2] + bfhi(q.y) * mreg[(base) + 3]  \
         + bflo(q.z) * mreg[(base) + 4] + bfhi(q.z) * mreg[(base) + 5]  \
         + bflo(q.w) * mreg[(base) + 6] + bfhi(q.w) * mreg[(base) + 7];

// ---------------- K1: convert/swizzle weights ----------------
// WdG  [s<4][jp<8][o<1024][k<8], o=h*16+il, val = Wd[h][(s*16+il)*64+jp*8+k]
// decwY [mm<64][lane<64][k<4],   val = decw[mm*256 + k*64 + lane]
// EWmG [jp<8][h2<128][k<8],      val = enc_m_row(j=jp*8+k, h2)
__global__ void cvt_kernel(const float* __restrict__ Wdecw,
                           const float* __restrict__ decw,
                           const float* __restrict__ Wencw,
                           const float* __restrict__ bencw,
                           us_t* __restrict__ WdG, us_t* __restrict__ decwY,
                           us_t* __restrict__ EWmG) {
    int o = blockIdx.x * 256 + threadIdx.x;
    if (o < 262144) {
        int s = o >> 16;
        int idx = o & 65535;
        int k = idx & 7;
        int oo = (idx >> 3) & 1023;
        int jp = idx >> 13;
        int h = oo >> 4, il = oo & 15;
        int i = s * 16 + il;
        int j = jp * 8 + k;
        WdG[o] = f2bf(Wdecw[h * 4096 + i * 64 + j]);
    } else if (o < 278528) {
        int oo = o - 262144;
        int k = oo & 3, lane = (oo >> 2) & 63, mm = oo >> 8;
        decwY[oo] = f2bf(decw[mm * 256 + k * 64 + lane]);
    } else if (o < 286720) {
        int oo = o - 278528;
        int kk = oo & 7, h2 = (oo >> 3) & 127, jp = oo >> 10;
        int j = jp * 8 + kk;
        float v = (h2 < 64) ? Wencw[j * 64 + h2] : bencw[j * 64 + (h2 - 64)];
        EWmG[oo] = f2bf(v);
    }
}

// ---------------- K2: token contribution table ----------------
__global__ void build_T(const float* __restrict__ emb, const float* __restrict__ Wencw,
                        const float* __restrict__ bencw, float* __restrict__ T) {
    int l = blockIdx.x >> 8, v = blockIdx.x & 255, h2 = threadIdx.x;  // h2 < 128
    float acc = 0.f;
#pragma unroll
    for (int e = 0; e < 16; ++e) {
        int d = 64 + l * 16 + e;
        float w = (h2 < 64) ? Wencw[d * 64 + h2] : bencw[d * 64 + (h2 - 64)];
        acc += emb[v * 16 + e] * w;
    }
    T[blockIdx.x * 128 + h2] = acc;
}

// ---------------- K3: window precompute P (f32, as R4) ----------------
__global__ void build_P(const float* __restrict__ T, const int* __restrict__ x0,
                        const float* __restrict__ Wencb, const float* __restrict__ bencb,
                        float* __restrict__ P) {
    int t = blockIdx.x >> 4, b = blockIdx.x & 15, h2 = threadIdx.x;  // h2 < 128
    float acc = (h2 < 64) ? Wencb[h2] : bencb[h2 - 64];
    for (int l = 0; l < 64; ++l) {
        int p = t + l;
        int v = (p < 64) ? 0 : x0[b * 2048 + (p - 64)];
        acc += T[(l * 256 + v) * 128 + h2];
    }
    P[blockIdx.x * 128 + h2] = acc;
}

// ---------------- K4: sequential recurrence (R4 body) ----------------
// grid 64: b = blk&15, s = blk>>4. 157.5 KB dynamic LDS -> 1 WG/CU.
__global__ __launch_bounds__(512) void recur(
    const float* __restrict__ bdecw, const float* __restrict__ bdecb,
    const float* __restrict__ Wdecb, const us_t* __restrict__ WdG,
    const us_t* __restrict__ EWmG, const float* __restrict__ P,
    u64_t* __restrict__ mhb) {
    const int b = blockIdx.x & 15, s = blockIdx.x >> 4;
    const int tid = threadIdx.x;

    extern __shared__ char smem[];
    us_t*  Wd_lds = (us_t*)smem;                  // 131072 B
    us_t*  EWm2   = (us_t*)(smem + 131072);       // 16384 B [jp][h2][8]
    us_t*  wdbt_s = (us_t*)(smem + 147456);       // 2176 B  [j][il], stride 17
    us_t*  bdec_s = (us_t*)(smem + 149632);       // 2176 B  [h][il], stride 17
    float* hw_s   = (float*)(smem + 151808);      // 256 B
    float* hb_s   = (float*)(smem + 152064);      // 256 B
    float* m_s    = (float*)(smem + 152320);      // 256 B (16B-aligned)
    float* V_s    = (float*)(smem + 152576);      // 4352 B  [h][il], stride 17
    float* rp_s   = (float*)(smem + 156928);      // 512 B   [p<8][il]
    float* bias_s = (float*)(smem + 157440);      // 64 B
    // total 157504

    // ---- init ----
    {
        const uint4* g4 = (const uint4*)WdG + s * 8192;
        uint4* l4 = (uint4*)Wd_lds;
        for (int k = tid; k < 8192; k += 512) l4[k] = g4[k];
    }
    {
        const uint4* g4 = (const uint4*)EWmG;
        uint4* l4 = (uint4*)EWm2;
        for (int k = tid; k < 1024; k += 512) l4[k] = g4[k];
    }
    for (int k = tid; k < 1024; k += 512) {
        int j = k >> 4, il = k & 15;
        wdbt_s[j * 17 + il] = f2bf(Wdecb[(s * 16 + il) * 64 + j]);  // W_dec_b[i][j]
        bdec_s[j * 17 + il] = f2bf(bdecw[j * 64 + s * 16 + il]);    // b_dec_w[h][i]
    }
    if (tid < 16) bias_s[tid] = bdecb[s * 16 + tid];
    if (tid < 64) m_s[tid] = 0.f;
    __syncthreads();

    // mreg: persistent, compile-time-constant indexing ONLY (Round-3 lesson:
    // any runtime index demotes the array to 17 GB of scratch traffic).
    float mreg[64];
#pragma unroll
    for (int j = 0; j < 64; ++j) mreg[j] = 0.f;

    float preg = 0.f;
    if (tid < 128) preg = P[b * 128 + tid];  // t = 0

    const uint4* Wd4 = (const uint4*)Wd_lds;
    const uint4* EW4 = (const uint4*)EWm2;
    const int hA = tid >> 4, ilA = tid & 15;

    for (int t = 0; t < 2048; ++t) {
        // ---- phase A: prefetch P(t+1), V slice, henc ----
        float pnext = 0.f;
        int tp = (t < 2047) ? (t + 1) : 2047;
        if (tid < 128) pnext = P[(tp * 16 + b) * 128 + tid];

        float a0 = 0.f, a1 = 0.f;
#pragma unroll
        for (int jp = 0; jp < 8; ++jp) {
            uint4 q0 = Wd4[jp * 1024 + tid];
            uint4 q1 = Wd4[jp * 1024 + tid + 512];
            MAC8(q0, jp * 8, a0);
            MAC8(q1, jp * 8, a1);
        }
        V_s[hA * 17 + ilA] = a0;
        V_s[(hA + 32) * 17 + ilA] = a1;

        if (tid < 128) {
            float acc = preg;
#pragma unroll
            for (int jp = 0; jp < 8; ++jp) {
                uint4 e = EW4[jp * 128 + tid];
                MAC8(e, jp * 8, acc);
            }
            float sg = 1.f / (1.f + __expf(-acc));
            if (tid < 64) hw_s[tid] = sg; else hb_s[tid - 64] = sg;
        }
        preg = pnext;
        __syncthreads();

        // ---- phase B: r partials on 128 threads (m from LDS) ----
        if (tid < 128) {
            int il = tid & 15, q = (tid >> 4) & 3;
            if (tid < 64) {
                float r = 0.f;
#pragma unroll
                for (int hh = 0; hh < 16; ++hh) {
                    int h = q * 16 + hh;
                    r += hw_s[h] * V_s[h * 17 + il];
                }
                rp_s[q * 16 + il] = r;
            } else {
                float r = 0.f;
#pragma unroll
                for (int kk = 0; kk < 16; ++kk) {
                    int jh = q * 16 + kk;
                    r += m_s[jh] * bf2f(wdbt_s[jh * 17 + il]);
                    r += hb_s[jh] * bf2f(bdec_s[jh * 17 + il]);
                }
                rp_s[64 + q * 16 + il] = r;
            }
        }
        __syncthreads();

        // ---- phase C + poison-mailbox exchange (wave 0; THE R9 change) ----
        if (tid < 64) {
            u64_t* row = mhb + (u64_t)(t * 16 + b) * 16;  // 16 u64 = 64 bf16
            float nmf = 0.f;
            if (tid < 16) {
                float r = bias_s[tid];
#pragma unroll
                for (int p = 0; p < 8; ++p) r += rp_s[p * 16 + tid];
                nmf = 1.f / (1.f + __expf(-r));
            }
            us_t nb = f2bf(nmf);                 // bf16-round: all WGs agree
            if (tid < 16) m_s[s * 16 + tid] = bf2f(nb);   // own slice, local
            // shfl-pack: lane k<4 gathers lanes 4k..4k+3 into one u64
            uint_t nbu = (uint_t)nb;
            uint_t w0 = (uint_t)__shfl((int)nbu, (tid & 3) * 4 + 0, 64);
            uint_t w1 = (uint_t)__shfl((int)nbu, (tid & 3) * 4 + 1, 64);
            uint_t w2 = (uint_t)__shfl((int)nbu, (tid & 3) * 4 + 2, 64);
            uint_t w3 = (uint_t)__shfl((int)nbu, (tid & 3) * 4 + 3, 64);
            if (tid < 4) {
                u64_t pay = (u64_t)w0 | ((u64_t)w1 << 16)
                          | ((u64_t)w2 << 32) | ((u64_t)w3 << 48);
                __hip_atomic_store(row + s * 4 + tid, pay,
                                   __ATOMIC_RELAXED, __HIP_MEMORY_SCOPE_AGENT);
            }
            // poll: lanes 0..15 load the whole row (one coalesced 128-B op);
            // a word is valid iff != poison (sigmoid bf16 can't be 0xAAAA).
            const bool self = (tid >> 2) == s;
            u64_t vk = 0;
            for (;;) {
                if (tid < 16 && !self)
                    vk = __hip_atomic_load(row + tid, __ATOMIC_RELAXED,
                                           __HIP_MEMORY_SCOPE_AGENT);
                bool ok = (tid >= 16) || self || (vk != POISON64);
                if (__ballot(ok) == ~0ull) break;
                __builtin_amdgcn_s_sleep(1);
            }
            if (tid < 16 && !self) {
                float4 mv;
                mv.x = bf2f((us_t)(vk & 0xFFFFu));
                mv.y = bf2f((us_t)((vk >> 16) & 0xFFFFu));
                mv.z = bf2f((us_t)((vk >> 32) & 0xFFFFu));
                mv.w = bf2f((us_t)(vk >> 48));
                ((float4*)m_s)[tid] = mv;
            }
        }
        __syncthreads();

        // ---- broadcast m from LDS into persistent registers ----
        {
            const float4* mg = (const float4*)m_s;
#pragma unroll
            for (int p = 0; p < 16; ++p) {
                float4 v = mg[p];
                mreg[p * 4 + 0] = v.x;
                mreg[p * 4 + 1] = v.y;
                mreg[p * 4 + 2] = v.z;
                mreg[p * 4 + 3] = v.w;
            }
        }
    }
}

// ---------------- K5: parallel loss (reads bf16 mailbox) ----------------
__global__ __launch_bounds__(256) void loss_kernel(
    const us_t* __restrict__ mhb, const us_t* __restrict__ decwY,
    const float* __restrict__ decb, const int* __restrict__ x0,
    float* __restrict__ out) {
    __shared__ __align__(16) us_t dw[16384];   // [mm][lane][k<4] bf16
    const int tid = threadIdx.x;
    {
        const uint4* g4 = (const uint4*)decwY;
        uint4* l4 = (uint4*)dw;
        for (int k = tid; k < 2048; k += 256) l4[k] = g4[k];
    }
    __syncthreads();
    const int lane = tid & 63, wv = tid >> 6;
    const uint2* dwu2 = (const uint2*)dw;
    float b0 = decb[lane], b1 = decb[lane + 64];
    float b2 = decb[lane + 128], b3 = decb[lane + 192];
    for (int r = 0; r < 8; ++r) {
        int row = blockIdx.x * 32 + wv * 8 + r;
        float mL = bf2f(mhb[row * 64 + lane]);
        float l0 = b0, l1 = b1, l2 = b2, l3 = b3;
#pragma unroll
        for (int mm = 0; mm < 64; ++mm) {
            float mv = __shfl(mL, mm, 64);
            uint2 q = dwu2[mm * 64 + lane];
            l0 += mv * bflo(q.x);
            l1 += mv * bfhi(q.x);
            l2 += mv * bflo(q.y);
            l3 += mv * bfhi(q.y);
        }
        float mx = fmaxf(fmaxf(l0, l1), fmaxf(l2, l3));
#pragma unroll
        for (int o = 32; o > 0; o >>= 1) mx = fmaxf(mx, __shfl_xor(mx, o, 64));
        float se = __expf(l0 - mx) + __expf(l1 - mx) + __expf(l2 - mx) + __expf(l3 - mx);
#pragma unroll
        for (int o = 32; o > 0; o >>= 1) se += __shfl_xor(se, o, 64);
        float lse = mx + __logf(se);
        int t = row >> 4, bb = row & 15;
        int y = x0[bb * 2048 + t];
        int hi = y >> 6;
        float cand = hi == 0 ? l0 : (hi == 1 ? l1 : (hi == 2 ? l2 : l3));
        float ly = __shfl(cand, y & 63, 64);
        if (lane == 0) out[row] = (lse - ly) * 1.4426950408889634f;
    }
}

extern "C" void kernel_launch(void* const* d_in, const int* in_sizes, int n_in,
                              void* d_out, int out_size, void* d_ws, size_t ws_size,
                              hipStream_t stream) {
    const int*   x0    = (const int*)d_in[0];
    const float* emb   = (const float*)d_in[1];
    const float* Wencw = (const float*)d_in[2];
    const float* Wencb = (const float*)d_in[3];
    const float* Wdecw = (const float*)d_in[4];
    const float* Wdecb = (const float*)d_in[5];
    const float* bencw = (const float*)d_in[6];
    const float* bencb = (const float*)d_in[7];
    const float* bdecw = (const float*)d_in[8];
    const float* bdecb = (const float*)d_in[9];
    const float* decw  = (const float*)d_in[10];
    const float* decb  = (const float*)d_in[11];
    float* out = (float*)d_out;

    char* ws = (char*)d_ws;
    us_t*  WdG   = (us_t*)(ws);                 //       0 .. 524288
    us_t*  decwY = (us_t*)(ws + 524288);        //  524288 .. 557056
    us_t*  EWmG  = (us_t*)(ws + 557056);        //  557056 .. 573440 (16 KB)
    float* T     = (float*)(ws + 573440);       //  573440 .. 8962048 (8 MB)
    u64_t* mhb   = (u64_t*)T;                   //  alias: T dead after build_P
    float* P     = (float*)(ws + 8962048);      // 8962048 .. 25739264 (16 MB)

    static const int kRecurLds = 157504;
    hipFuncSetAttribute((const void*)recur,
                        hipFuncAttributeMaxDynamicSharedMemorySize, kRecurLds);

    cvt_kernel<<<1120, 256, 0, stream>>>(Wdecw, decw, Wencw, bencw,
                                         WdG, decwY, EWmG);
    build_T<<<16384, 128, 0, stream>>>(emb, Wencw, bencw, T);
    build_P<<<32768, 128, 0, stream>>>(T, x0, Wencb, bencb, P);
    // poison the mailbox AFTER build_P (mhb aliases T), BEFORE recur
    hipMemsetAsync(mhb, 0xAA, 4194304, stream);
    recur<<<64, 512, kRecurLds, stream>>>(bdecw, bdecb, Wdecb, WdG, EWmG,
                                          P, mhb);
    loss_kernel<<<1024, 256, 0, stream>>>((const us_t*)mhb, decwY, decb, x0, out);
}

// Round 11
// 4290.514 us; speedup vs baseline: 2.2119x; 1.2489x over previous
//
#include <hip/hip_runtime.h>
#include <hip/hip_bf16.h>
#include <hip/hip_fp16.h>

// Hypernetwork RNN scan. B=16, N=2048, M=H=64, L*E=1024, Cout=256.
// Round 11: R10 retry (compile fix only). R9 body (best: 5.36 ms) + phase A
// in f16 with v_dot2_f32_f16. The pkrtz builtin's return type clashed with
// the h2_t typedef; replaced with two v_cvt_f16_f32 (f2h) packs — exact,
// since m values are f16-rounded by construction.
//   K1 cvt: Wd->f16 slice layout; enc m-rows->f16; dec_w->bf16 (loss)
//   K2 build_T (f32, 8 MB), K3 build_P (f32, 16 MB)
//   K4 recur: 64 WGs = 16 batches x 4 i-slices; LDS-Wd; poison-mailbox
//   K5 loss:  parallel logits/LSE/NLL over the f16 m mailbox

typedef unsigned int uint_t;
typedef unsigned short us_t;
typedef unsigned long long u64_t;
typedef _Float16 h2_t __attribute__((ext_vector_type(2)));

#define POISON64 0xAAAAAAAAAAAAAAAAULL

__device__ __forceinline__ us_t f2bf(float f) {
    uint_t u = __float_as_uint(f);
    uint_t r = u + 0x7fffu + ((u >> 16) & 1u);   // RNE
    return (us_t)(r >> 16);
}
__device__ __forceinline__ float bf2f(us_t s) {
    return __uint_as_float(((uint_t)s) << 16);
}
__device__ __forceinline__ float bflo(uint_t u) { return __uint_as_float(u << 16); }
__device__ __forceinline__ float bfhi(uint_t u) { return __uint_as_float(u & 0xffff0000u); }

__device__ __forceinline__ us_t f2h(float f) {
    __half h = __float2half(f);                  // RNE
    return *reinterpret_cast<us_t*>(&h);
}
__device__ __forceinline__ float h2f(us_t s) {
    __half h = *reinterpret_cast<__half*>(&s);
    return __half2float(h);
}
__device__ __forceinline__ h2_t u2h2(uint_t u) {
    union { uint_t u; h2_t h; } x; x.u = u; return x.h;
}

// dot2: two f16 MACs into an f32 accumulator in one instruction.
#if __has_builtin(__builtin_amdgcn_fdot2)
__device__ __forceinline__ float dot2f(uint_t a, uint_t b, float c) {
    return __builtin_amdgcn_fdot2(u2h2(a), u2h2(b), c, false);
}
#else
__device__ __forceinline__ float dot2f(uint_t a, uint_t b, float c) {
    h2_t x = u2h2(a), y = u2h2(b);
    return c + (float)x.x * (float)y.x + (float)x.y * (float)y.y;
}
#endif

// q (uint4 = 8 f16 weights, j = jp*8..jp*8+7) dot m-pairs mreg2u[jp*4+0..3]
#define DOT4(q, base, acc)                                              \
    acc = dot2f(q.x, mreg2u[(base) + 0], acc);                          \
    acc = dot2f(q.y, mreg2u[(base) + 1], acc);                          \
    acc = dot2f(q.z, mreg2u[(base) + 2], acc);                          \
    acc = dot2f(q.w, mreg2u[(base) + 3], acc);

// ---------------- K1: convert/swizzle weights ----------------
// WdG  [s<4][jp<8][o<1024][k<8] f16, o=h*16+il, val = Wd[h][(s*16+il)*64+jp*8+k]
// decwY [mm<64][lane<64][k<4] bf16,  val = decw[mm*256 + k*64 + lane]
// EWmG [jp<8][h2<128][k<8] f16,      val = enc_m_row(j=jp*8+k, h2)
__global__ void cvt_kernel(const float* __restrict__ Wdecw,
                           const float* __restrict__ decw,
                           const float* __restrict__ Wencw,
                           const float* __restrict__ bencw,
                           us_t* __restrict__ WdG, us_t* __restrict__ decwY,
                           us_t* __restrict__ EWmG) {
    int o = blockIdx.x * 256 + threadIdx.x;
    if (o < 262144) {
        int s = o >> 16;
        int idx = o & 65535;
        int k = idx & 7;
        int oo = (idx >> 3) & 1023;
        int jp = idx >> 13;
        int h = oo >> 4, il = oo & 15;
        int i = s * 16 + il;
        int j = jp * 8 + k;
        WdG[o] = f2h(Wdecw[h * 4096 + i * 64 + j]);
    } else if (o < 278528) {
        int oo = o - 262144;
        int k = oo & 3, lane = (oo >> 2) & 63, mm = oo >> 8;
        decwY[oo] = f2bf(decw[mm * 256 + k * 64 + lane]);
    } else if (o < 286720) {
        int oo = o - 278528;
        int kk = oo & 7, h2 = (oo >> 3) & 127, jp = oo >> 10;
        int j = jp * 8 + kk;
        float v = (h2 < 64) ? Wencw[j * 64 + h2] : bencw[j * 64 + (h2 - 64)];
        EWmG[oo] = f2h(v);
    }
}

// ---------------- K2: token contribution table ----------------
__global__ void build_T(const float* __restrict__ emb, const float* __restrict__ Wencw,
                        const float* __restrict__ bencw, float* __restrict__ T) {
    int l = blockIdx.x >> 8, v = blockIdx.x & 255, h2 = threadIdx.x;  // h2 < 128
    float acc = 0.f;
#pragma unroll
    for (int e = 0; e < 16; ++e) {
        int d = 64 + l * 16 + e;
        float w = (h2 < 64) ? Wencw[d * 64 + h2] : bencw[d * 64 + (h2 - 64)];
        acc += emb[v * 16 + e] * w;
    }
    T[blockIdx.x * 128 + h2] = acc;
}

// ---------------- K3: window precompute P (f32) ----------------
__global__ void build_P(const float* __restrict__ T, const int* __restrict__ x0,
                        const float* __restrict__ Wencb, const float* __restrict__ bencb,
                        float* __restrict__ P) {
    int t = blockIdx.x >> 4, b = blockIdx.x & 15, h2 = threadIdx.x;  // h2 < 128
    float acc = (h2 < 64) ? Wencb[h2] : bencb[h2 - 64];
    for (int l = 0; l < 64; ++l) {
        int p = t + l;
        int v = (p < 64) ? 0 : x0[b * 2048 + (p - 64)];
        acc += T[(l * 256 + v) * 128 + h2];
    }
    P[blockIdx.x * 128 + h2] = acc;
}

// ---------------- K4: sequential recurrence (R9 body, f16 phase A) -------
// grid 64: b = blk&15, s = blk>>4. 157.6 KB dynamic LDS -> 1 WG/CU.
__global__ __launch_bounds__(512) void recur(
    const float* __restrict__ bdecw, const float* __restrict__ bdecb,
    const float* __restrict__ Wdecb, const us_t* __restrict__ WdG,
    const us_t* __restrict__ EWmG, const float* __restrict__ P,
    u64_t* __restrict__ mhb) {
    const int b = blockIdx.x & 15, s = blockIdx.x >> 4;
    const int tid = threadIdx.x;

    extern __shared__ char smem[];
    us_t*   Wd_lds = (us_t*)smem;                  // 131072 B (f16)
    us_t*   EWm2   = (us_t*)(smem + 131072);       // 16384 B [jp][h2][8] f16
    us_t*   wdbt_s = (us_t*)(smem + 147456);       // 2176 B  [j][il], stride 17
    us_t*   bdec_s = (us_t*)(smem + 149632);       // 2176 B  [h][il], stride 17
    float*  hw_s   = (float*)(smem + 151808);      // 256 B
    float*  hb_s   = (float*)(smem + 152064);      // 256 B
    float*  m_s    = (float*)(smem + 152320);      // 256 B f32 (phase B)
    float*  V_s    = (float*)(smem + 152576);      // 4352 B  [h][il], stride 17
    float*  rp_s   = (float*)(smem + 156928);      // 512 B   [p<8][il]
    float*  bias_s = (float*)(smem + 157440);      // 64 B
    uint_t* m2_s   = (uint_t*)(smem + 157504);     // 128 B packed half2 (phase A)
    // total 157632

    // ---- init ----
    {
        const uint4* g4 = (const uint4*)WdG + s * 8192;
        uint4* l4 = (uint4*)Wd_lds;
        for (int k = tid; k < 8192; k += 512) l4[k] = g4[k];
    }
    {
        const uint4* g4 = (const uint4*)EWmG;
        uint4* l4 = (uint4*)EWm2;
        for (int k = tid; k < 1024; k += 512) l4[k] = g4[k];
    }
    for (int k = tid; k < 1024; k += 512) {
        int j = k >> 4, il = k & 15;
        wdbt_s[j * 17 + il] = f2bf(Wdecb[(s * 16 + il) * 64 + j]);  // W_dec_b[i][j]
        bdec_s[j * 17 + il] = f2bf(bdecw[j * 64 + s * 16 + il]);    // b_dec_w[h][i]
    }
    if (tid < 16) bias_s[tid] = bdecb[s * 16 + tid];
    if (tid < 64) m_s[tid] = 0.f;
    if (tid < 32) m2_s[tid] = 0u;
    __syncthreads();

    // persistent m as 32 packed half2 regs; constant indexing ONLY
    // (Round-3 lesson: runtime index => scratch demotion => 17 GB traffic).
    uint_t mreg2u[32];
#pragma unroll
    for (int j = 0; j < 32; ++j) mreg2u[j] = 0u;

    float preg = 0.f;
    if (tid < 128) preg = P[b * 128 + tid];  // t = 0

    const uint4* Wd4 = (const uint4*)Wd_lds;
    const uint4* EW4 = (const uint4*)EWm2;
    const int hA = tid >> 4, ilA = tid & 15;

    for (int t = 0; t < 2048; ++t) {
        // ---- phase A: prefetch P(t+1), V slice, henc (f16 dot2) ----
        float pnext = 0.f;
        int tp = (t < 2047) ? (t + 1) : 2047;
        if (tid < 128) pnext = P[(tp * 16 + b) * 128 + tid];

        float a0 = 0.f, a1 = 0.f;
#pragma unroll
        for (int jp = 0; jp < 8; ++jp) {
            uint4 q0 = Wd4[jp * 1024 + tid];
            uint4 q1 = Wd4[jp * 1024 + tid + 512];
            DOT4(q0, jp * 4, a0);
            DOT4(q1, jp * 4, a1);
        }
        V_s[hA * 17 + ilA] = a0;
        V_s[(hA + 32) * 17 + ilA] = a1;

        if (tid < 128) {
            float acc = preg;
#pragma unroll
            for (int jp = 0; jp < 8; ++jp) {
                uint4 e = EW4[jp * 128 + tid];
                DOT4(e, jp * 4, acc);
            }
            float sg = 1.f / (1.f + __expf(-acc));
            if (tid < 64) hw_s[tid] = sg; else hb_s[tid - 64] = sg;
        }
        preg = pnext;
        __syncthreads();

        // ---- phase B: r partials on 128 threads (m from f32 LDS) ----
        if (tid < 128) {
            int il = tid & 15, q = (tid >> 4) & 3;
            if (tid < 64) {
                float r = 0.f;
#pragma unroll
                for (int hh = 0; hh < 16; ++hh) {
                    int h = q * 16 + hh;
                    r += hw_s[h] * V_s[h * 17 + il];
                }
                rp_s[q * 16 + il] = r;
            } else {
                float r = 0.f;
#pragma unroll
                for (int kk = 0; kk < 16; ++kk) {
                    int jh = q * 16 + kk;
                    r += m_s[jh] * bf2f(wdbt_s[jh * 17 + il]);
                    r += hb_s[jh] * bf2f(bdec_s[jh * 17 + il]);
                }
                rp_s[64 + q * 16 + il] = r;
            }
        }
        __syncthreads();

        // ---- phase C + poison-mailbox exchange (wave 0) ----
        if (tid < 64) {
            u64_t* row = mhb + (u64_t)(t * 16 + b) * 16;  // 16 u64 = 64 f16
            float nmf = 0.f;
            if (tid < 16) {
                float r = bias_s[tid];
#pragma unroll
                for (int p = 0; p < 8; ++p) r += rp_s[p * 16 + tid];
                nmf = 1.f / (1.f + __expf(-r));
            }
            us_t nh = f2h(nmf);                  // f16-round: all WGs agree
            if (tid < 16) m_s[s * 16 + tid] = h2f(nh);    // own slice, f32
            // shfl-pack: lane k<4 gathers lanes 4k..4k+3 into one u64
            uint_t nhu = (uint_t)nh;
            uint_t w0 = (uint_t)__shfl((int)nhu, (tid & 3) * 4 + 0, 64);
            uint_t w1 = (uint_t)__shfl((int)nhu, (tid & 3) * 4 + 1, 64);
            uint_t w2 = (uint_t)__shfl((int)nhu, (tid & 3) * 4 + 2, 64);
            uint_t w3 = (uint_t)__shfl((int)nhu, (tid & 3) * 4 + 3, 64);
            if (tid < 4) {
                u64_t pay = (u64_t)w0 | ((u64_t)w1 << 16)
                          | ((u64_t)w2 << 32) | ((u64_t)w3 << 48);
                __hip_atomic_store(row + s * 4 + tid, pay,
                                   __ATOMIC_RELAXED, __HIP_MEMORY_SCOPE_AGENT);
            }
            // poll: lanes 0..15 load the whole row (one coalesced 128-B op);
            // valid iff != poison (f16 sigmoid has sign bit 0, never 0xAAAA).
            const bool self = (tid >> 2) == s;
            u64_t vk = 0;
            for (;;) {
                if (tid < 16 && !self)
                    vk = __hip_atomic_load(row + tid, __ATOMIC_RELAXED,
                                           __HIP_MEMORY_SCOPE_AGENT);
                bool ok = (tid >= 16) || self || (vk != POISON64);
                if (__ballot(ok) == ~0ull) break;
                __builtin_amdgcn_s_sleep(1);
            }
            if (tid < 16 && !self) {
                float4 mv;
                mv.x = h2f((us_t)(vk & 0xFFFFu));
                mv.y = h2f((us_t)((vk >> 16) & 0xFFFFu));
                mv.z = h2f((us_t)((vk >> 32) & 0xFFFFu));
                mv.w = h2f((us_t)(vk >> 48));
                ((float4*)m_s)[tid] = mv;
            }
            // build packed-half2 rep for phase A (two v_cvt_f16_f32; exact,
            // m values are already f16-rounded)
            __builtin_amdgcn_s_waitcnt(0xC07F);  // lgkmcnt(0): m_s visible in-wave
            if (tid < 32) {
                uint_t pk = (uint_t)f2h(m_s[2 * tid])
                          | ((uint_t)f2h(m_s[2 * tid + 1]) << 16);
                m2_s[tid] = pk;
            }
        }
        __syncthreads();

        // ---- broadcast packed m into persistent registers ----
        {
            const uint4* mg = (const uint4*)m2_s;
#pragma unroll
            for (int p = 0; p < 8; ++p) {
                uint4 v = mg[p];
                mreg2u[p * 4 + 0] = v.x;
                mreg2u[p * 4 + 1] = v.y;
                mreg2u[p * 4 + 2] = v.z;
                mreg2u[p * 4 + 3] = v.w;
            }
        }
    }
}

// ---------------- K5: parallel loss (reads f16 mailbox) ----------------
__global__ __launch_bounds__(256) void loss_kernel(
    const us_t* __restrict__ mhb, const us_t* __restrict__ decwY,
    const float* __restrict__ decb, const int* __restrict__ x0,
    float* __restrict__ out) {
    __shared__ __align__(16) us_t dw[16384];   // [mm][lane][k<4] bf16
    const int tid = threadIdx.x;
    {
        const uint4* g4 = (const uint4*)decwY;
        uint4* l4 = (uint4*)dw;
        for (int k = tid; k < 2048; k += 256) l4[k] = g4[k];
    }
    __syncthreads();
    const int lane = tid & 63, wv = tid >> 6;
    const uint2* dwu2 = (const uint2*)dw;
    float b0 = decb[lane], b1 = decb[lane + 64];
    float b2 = decb[lane + 128], b3 = decb[lane + 192];
    for (int r = 0; r < 8; ++r) {
        int row = blockIdx.x * 32 + wv * 8 + r;
        float mL = h2f(mhb[row * 64 + lane]);
        float l0 = b0, l1 = b1, l2 = b2, l3 = b3;
#pragma unroll
        for (int mm = 0; mm < 64; ++mm) {
            float mv = __shfl(mL, mm, 64);
            uint2 q = dwu2[mm * 64 + lane];
            l0 += mv * bflo(q.x);
            l1 += mv * bfhi(q.x);
            l2 += mv * bflo(q.y);
            l3 += mv * bfhi(q.y);
        }
        float mx = fmaxf(fmaxf(l0, l1), fmaxf(l2, l3));
#pragma unroll
        for (int o = 32; o > 0; o >>= 1) mx = fmaxf(mx, __shfl_xor(mx, o, 64));
        float se = __expf(l0 - mx) + __expf(l1 - mx) + __expf(l2 - mx) + __expf(l3 - mx);
#pragma unroll
        for (int o = 32; o > 0; o >>= 1) se += __shfl_xor(se, o, 64);
        float lse = mx + __logf(se);
        int t = row >> 4, bb = row & 15;
        int y = x0[bb * 2048 + t];
        int hi = y >> 6;
        float cand = hi == 0 ? l0 : (hi == 1 ? l1 : (hi == 2 ? l2 : l3));
        float ly = __shfl(cand, y & 63, 64);
        if (lane == 0) out[row] = (lse - ly) * 1.4426950408889634f;
    }
}

extern "C" void kernel_launch(void* const* d_in, const int* in_sizes, int n_in,
                              void* d_out, int out_size, void* d_ws, size_t ws_size,
                              hipStream_t stream) {
    const int*   x0    = (const int*)d_in[0];
    const float* emb   = (const float*)d_in[1];
    const float* Wencw = (const float*)d_in[2];
    const float* Wencb = (const float*)d_in[3];
    const float* Wdecw = (const float*)d_in[4];
    const float* Wdecb = (const float*)d_in[5];
    const float* bencw = (const float*)d_in[6];
    const float* bencb = (const float*)d_in[7];
    const float* bdecw = (const float*)d_in[8];
    const float* bdecb = (const float*)d_in[9];
    const float* decw  = (const float*)d_in[10];
    const float* decb  = (const float*)d_in[11];
    float* out = (float*)d_out;

    char* ws = (char*)d_ws;
    us_t*  WdG   = (us_t*)(ws);                 //       0 .. 524288
    us_t*  decwY = (us_t*)(ws + 524288);        //  524288 .. 557056
    us_t*  EWmG  = (us_t*)(ws + 557056);        //  557056 .. 573440 (16 KB)
    float* T     = (float*)(ws + 573440);       //  573440 .. 8962048 (8 MB)
    u64_t* mhb   = (u64_t*)T;                   //  alias: T dead after build_P
    float* P     = (float*)(ws + 8962048);      // 8962048 .. 25739264 (16 MB)

    static const int kRecurLds = 157632;
    (void)hipFuncSetAttribute((const void*)recur,
                              hipFuncAttributeMaxDynamicSharedMemorySize,
                              kRecurLds);

    cvt_kernel<<<1120, 256, 0, stream>>>(Wdecw, decw, Wencw, bencw,
                                         WdG, decwY, EWmG);
    build_T<<<16384, 128, 0, stream>>>(emb, Wencw, bencw, T);
    build_P<<<32768, 128, 0, stream>>>(T, x0, Wencb, bencb, P);
    // poison the mailbox AFTER build_P (mhb aliases T), BEFORE recur
    (void)hipMemsetAsync(mhb, 0xAA, 4194304, stream);
    recur<<<64, 512, kRecurLds, stream>>>(bdecw, bdecb, Wdecb, WdG, EWmG,
                                          P, mhb);
    loss_kernel<<<1024, 256, 0, stream>>>((const us_t*)mhb, decwY, decb, x0, out);
}

// Round 12
// 3964.152 us; speedup vs baseline: 2.3940x; 1.0823x over previous
//
#include <hip/hip_runtime.h>
#include <hip/hip_bf16.h>
#include <hip/hip_fp16.h>

// Hypernetwork RNN scan. B=16, N=2048, M=H=64, L*E=1024, Cout=256.
// Round 12: R11 body (best: 4.29 ms) + ONE change — Wd moves LDS -> VGPRs
// (wreg[16] uint4/thread). R11's phase A is LDS-port-bound (~1540 cyc/step
// streaming 131 KB of Wd vs ~860 cyc VALU). m stays in persistent packed-f16
// registers; EWm2 stays in LDS; the 157.6 KB dynamic-LDS request is kept as
// a dead pad so occupancy (1 WG/CU) is held constant. This also closes the
// R5-R8 mystery: those had Wd-regs AND per-jp m-from-LDS; with m-handling
// now fixed, the Wd source is isolated as the single variable.
//   K1 cvt: Wd->f16 slice layout; enc m-rows->f16; dec_w->bf16 (loss)
//   K2 build_T (f32, 8 MB), K3 build_P (f32, 16 MB)
//   K4 recur: 64 WGs = 16 batches x 4 i-slices; Wd in VGPRs; poison-mailbox
//   K5 loss:  parallel logits/LSE/NLL over the f16 m mailbox

typedef unsigned int uint_t;
typedef unsigned short us_t;
typedef unsigned long long u64_t;
typedef _Float16 h2_t __attribute__((ext_vector_type(2)));

#define POISON64 0xAAAAAAAAAAAAAAAAULL

__device__ __forceinline__ us_t f2bf(float f) {
    uint_t u = __float_as_uint(f);
    uint_t r = u + 0x7fffu + ((u >> 16) & 1u);   // RNE
    return (us_t)(r >> 16);
}
__device__ __forceinline__ float bf2f(us_t s) {
    return __uint_as_float(((uint_t)s) << 16);
}
__device__ __forceinline__ float bflo(uint_t u) { return __uint_as_float(u << 16); }
__device__ __forceinline__ float bfhi(uint_t u) { return __uint_as_float(u & 0xffff0000u); }

__device__ __forceinline__ us_t f2h(float f) {
    __half h = __float2half(f);                  // RNE
    return *reinterpret_cast<us_t*>(&h);
}
__device__ __forceinline__ float h2f(us_t s) {
    __half h = *reinterpret_cast<__half*>(&s);
    return __half2float(h);
}
__device__ __forceinline__ h2_t u2h2(uint_t u) {
    union { uint_t u; h2_t h; } x; x.u = u; return x.h;
}

// dot2: two f16 MACs into an f32 accumulator in one instruction.
#if __has_builtin(__builtin_amdgcn_fdot2)
__device__ __forceinline__ float dot2f(uint_t a, uint_t b, float c) {
    return __builtin_amdgcn_fdot2(u2h2(a), u2h2(b), c, false);
}
#else
__device__ __forceinline__ float dot2f(uint_t a, uint_t b, float c) {
    h2_t x = u2h2(a), y = u2h2(b);
    return c + (float)x.x * (float)y.x + (float)x.y * (float)y.y;
}
#endif

// q (uint4 = 8 f16 weights, j = jp*8..jp*8+7) dot m-pairs mreg2u[jp*4+0..3]
#define DOT4(q, base, acc)                                              \
    acc = dot2f(q.x, mreg2u[(base) + 0], acc);                          \
    acc = dot2f(q.y, mreg2u[(base) + 1], acc);                          \
    acc = dot2f(q.z, mreg2u[(base) + 2], acc);                          \
    acc = dot2f(q.w, mreg2u[(base) + 3], acc);

// ---------------- K1: convert/swizzle weights ----------------
// WdG  [s<4][jp<8][o<1024][k<8] f16, o=h*16+il, val = Wd[h][(s*16+il)*64+jp*8+k]
// decwY [mm<64][lane<64][k<4] bf16,  val = decw[mm*256 + k*64 + lane]
// EWmG [jp<8][h2<128][k<8] f16,      val = enc_m_row(j=jp*8+k, h2)
__global__ void cvt_kernel(const float* __restrict__ Wdecw,
                           const float* __restrict__ decw,
                           const float* __restrict__ Wencw,
                           const float* __restrict__ bencw,
                           us_t* __restrict__ WdG, us_t* __restrict__ decwY,
                           us_t* __restrict__ EWmG) {
    int o = blockIdx.x * 256 + threadIdx.x;
    if (o < 262144) {
        int s = o >> 16;
        int idx = o & 65535;
        int k = idx & 7;
        int oo = (idx >> 3) & 1023;
        int jp = idx >> 13;
        int h = oo >> 4, il = oo & 15;
        int i = s * 16 + il;
        int j = jp * 8 + k;
        WdG[o] = f2h(Wdecw[h * 4096 + i * 64 + j]);
    } else if (o < 278528) {
        int oo = o - 262144;
        int k = oo & 3, lane = (oo >> 2) & 63, mm = oo >> 8;
        decwY[oo] = f2bf(decw[mm * 256 + k * 64 + lane]);
    } else if (o < 286720) {
        int oo = o - 278528;
        int kk = oo & 7, h2 = (oo >> 3) & 127, jp = oo >> 10;
        int j = jp * 8 + kk;
        float v = (h2 < 64) ? Wencw[j * 64 + h2] : bencw[j * 64 + (h2 - 64)];
        EWmG[oo] = f2h(v);
    }
}

// ---------------- K2: token contribution table ----------------
__global__ void build_T(const float* __restrict__ emb, const float* __restrict__ Wencw,
                        const float* __restrict__ bencw, float* __restrict__ T) {
    int l = blockIdx.x >> 8, v = blockIdx.x & 255, h2 = threadIdx.x;  // h2 < 128
    float acc = 0.f;
#pragma unroll
    for (int e = 0; e < 16; ++e) {
        int d = 64 + l * 16 + e;
        float w = (h2 < 64) ? Wencw[d * 64 + h2] : bencw[d * 64 + (h2 - 64)];
        acc += emb[v * 16 + e] * w;
    }
    T[blockIdx.x * 128 + h2] = acc;
}

// ---------------- K3: window precompute P (f32) ----------------
__global__ void build_P(const float* __restrict__ T, const int* __restrict__ x0,
                        const float* __restrict__ Wencb, const float* __restrict__ bencb,
                        float* __restrict__ P) {
    int t = blockIdx.x >> 4, b = blockIdx.x & 15, h2 = threadIdx.x;  // h2 < 128
    float acc = (h2 < 64) ? Wencb[h2] : bencb[h2 - 64];
    for (int l = 0; l < 64; ++l) {
        int p = t + l;
        int v = (p < 64) ? 0 : x0[b * 2048 + (p - 64)];
        acc += T[(l * 256 + v) * 128 + h2];
    }
    P[blockIdx.x * 128 + h2] = acc;
}

// ---------------- K4: sequential recurrence (Wd in VGPRs) ----------------
// grid 64: b = blk&15, s = blk>>4. 157.6 KB dynamic LDS (mostly dead pad)
// -> 1 WG/CU held constant vs R11. (512,2) lifts the VGPR cap for wreg.
__global__ __launch_bounds__(512, 2) void recur(
    const float* __restrict__ bdecw, const float* __restrict__ bdecb,
    const float* __restrict__ Wdecb, const us_t* __restrict__ WdG,
    const us_t* __restrict__ EWmG, const float* __restrict__ P,
    u64_t* __restrict__ mhb) {
    const int b = blockIdx.x & 15, s = blockIdx.x >> 4;
    const int tid = threadIdx.x;

    extern __shared__ char smem[];
    // smem+0 .. +131072: dead pad (was Wd_lds) — keeps 1 WG/CU occupancy
    us_t*   EWm2   = (us_t*)(smem + 131072);       // 16384 B [jp][h2][8] f16
    us_t*   wdbt_s = (us_t*)(smem + 147456);       // 2176 B  [j][il], stride 17
    us_t*   bdec_s = (us_t*)(smem + 149632);       // 2176 B  [h][il], stride 17
    float*  hw_s   = (float*)(smem + 151808);      // 256 B
    float*  hb_s   = (float*)(smem + 152064);      // 256 B
    float*  m_s    = (float*)(smem + 152320);      // 256 B f32 (phase B)
    float*  V_s    = (float*)(smem + 152576);      // 4352 B  [h][il], stride 17
    float*  rp_s   = (float*)(smem + 156928);      // 512 B   [p<8][il]
    float*  bias_s = (float*)(smem + 157440);      // 64 B
    uint_t* m2_s   = (uint_t*)(smem + 157504);     // 128 B packed half2 (phase A)
    // total 157632

    // ---- init: Wd slice -> REGISTERS (rows o=tid and o=tid+512) ----
    uint4 wreg[16];
    {
        const uint4* g4 = (const uint4*)WdG + s * 8192;
#pragma unroll
        for (int jp = 0; jp < 8; ++jp) {
            wreg[jp]     = g4[jp * 1024 + tid];
            wreg[8 + jp] = g4[jp * 1024 + tid + 512];
        }
    }
    {
        const uint4* g4 = (const uint4*)EWmG;
        uint4* l4 = (uint4*)EWm2;
        for (int k = tid; k < 1024; k += 512) l4[k] = g4[k];
    }
    for (int k = tid; k < 1024; k += 512) {
        int j = k >> 4, il = k & 15;
        wdbt_s[j * 17 + il] = f2bf(Wdecb[(s * 16 + il) * 64 + j]);  // W_dec_b[i][j]
        bdec_s[j * 17 + il] = f2bf(bdecw[j * 64 + s * 16 + il]);    // b_dec_w[h][i]
    }
    if (tid < 16) bias_s[tid] = bdecb[s * 16 + tid];
    if (tid < 64) m_s[tid] = 0.f;
    if (tid < 32) m2_s[tid] = 0u;
    __syncthreads();

    // persistent m as 32 packed half2 regs; constant indexing ONLY
    // (Round-3 lesson: runtime index => scratch demotion => 17 GB traffic).
    uint_t mreg2u[32];
#pragma unroll
    for (int j = 0; j < 32; ++j) mreg2u[j] = 0u;

    float preg = 0.f;
    if (tid < 128) preg = P[b * 128 + tid];  // t = 0

    const uint4* EW4 = (const uint4*)EWm2;
    const int hA = tid >> 4, ilA = tid & 15;

    for (int t = 0; t < 2048; ++t) {
        // ---- phase A: prefetch P(t+1), V slice (regs), henc (f16 dot2) ----
        float pnext = 0.f;
        int tp = (t < 2047) ? (t + 1) : 2047;
        if (tid < 128) pnext = P[(tp * 16 + b) * 128 + tid];

        float a0 = 0.f, a1 = 0.f;
#pragma unroll
        for (int jp = 0; jp < 8; ++jp) {
            uint4 q0 = wreg[jp];
            uint4 q1 = wreg[8 + jp];
            DOT4(q0, jp * 4, a0);
            DOT4(q1, jp * 4, a1);
        }
        V_s[hA * 17 + ilA] = a0;
        V_s[(hA + 32) * 17 + ilA] = a1;

        if (tid < 128) {
            float acc = preg;
#pragma unroll
            for (int jp = 0; jp < 8; ++jp) {
                uint4 e = EW4[jp * 128 + tid];
                DOT4(e, jp * 4, acc);
            }
            float sg = 1.f / (1.f + __expf(-acc));
            if (tid < 64) hw_s[tid] = sg; else hb_s[tid - 64] = sg;
        }
        preg = pnext;
        __syncthreads();

        // ---- phase B: r partials on 128 threads (m from f32 LDS) ----
        if (tid < 128) {
            int il = tid & 15, q = (tid >> 4) & 3;
            if (tid < 64) {
                float r = 0.f;
#pragma unroll
                for (int hh = 0; hh < 16; ++hh) {
                    int h = q * 16 + hh;
                    r += hw_s[h] * V_s[h * 17 + il];
                }
                rp_s[q * 16 + il] = r;
            } else {
                float r = 0.f;
#pragma unroll
                for (int kk = 0; kk < 16; ++kk) {
                    int jh = q * 16 + kk;
                    r += m_s[jh] * bf2f(wdbt_s[jh * 17 + il]);
                    r += hb_s[jh] * bf2f(bdec_s[jh * 17 + il]);
                }
                rp_s[64 + q * 16 + il] = r;
            }
        }
        __syncthreads();

        // ---- phase C + poison-mailbox exchange (wave 0) ----
        if (tid < 64) {
            u64_t* row = mhb + (u64_t)(t * 16 + b) * 16;  // 16 u64 = 64 f16
            float nmf = 0.f;
            if (tid < 16) {
                float r = bias_s[tid];
#pragma unroll
                for (int p = 0; p < 8; ++p) r += rp_s[p * 16 + tid];
                nmf = 1.f / (1.f + __expf(-r));
            }
            us_t nh = f2h(nmf);                  // f16-round: all WGs agree
            if (tid < 16) m_s[s * 16 + tid] = h2f(nh);    // own slice, f32
            // shfl-pack: lane k<4 gathers lanes 4k..4k+3 into one u64
            uint_t nhu = (uint_t)nh;
            uint_t w0 = (uint_t)__shfl((int)nhu, (tid & 3) * 4 + 0, 64);
            uint_t w1 = (uint_t)__shfl((int)nhu, (tid & 3) * 4 + 1, 64);
            uint_t w2 = (uint_t)__shfl((int)nhu, (tid & 3) * 4 + 2, 64);
            uint_t w3 = (uint_t)__shfl((int)nhu, (tid & 3) * 4 + 3, 64);
            if (tid < 4) {
                u64_t pay = (u64_t)w0 | ((u64_t)w1 << 16)
                          | ((u64_t)w2 << 32) | ((u64_t)w3 << 48);
                __hip_atomic_store(row + s * 4 + tid, pay,
                                   __ATOMIC_RELAXED, __HIP_MEMORY_SCOPE_AGENT);
            }
            // poll: lanes 0..15 load the whole row (one coalesced 128-B op);
            // valid iff != poison (f16 sigmoid has sign bit 0, never 0xAAAA).
            const bool self = (tid >> 2) == s;
            u64_t vk = 0;
            for (;;) {
                if (tid < 16 && !self)
                    vk = __hip_atomic_load(row + tid, __ATOMIC_RELAXED,
                                           __HIP_MEMORY_SCOPE_AGENT);
                bool ok = (tid >= 16) || self || (vk != POISON64);
                if (__ballot(ok) == ~0ull) break;
                __builtin_amdgcn_s_sleep(1);
            }
            if (tid < 16 && !self) {
                float4 mv;
                mv.x = h2f((us_t)(vk & 0xFFFFu));
                mv.y = h2f((us_t)((vk >> 16) & 0xFFFFu));
                mv.z = h2f((us_t)((vk >> 32) & 0xFFFFu));
                mv.w = h2f((us_t)(vk >> 48));
                ((float4*)m_s)[tid] = mv;
            }
            // build packed-half2 rep for phase A (two v_cvt_f16_f32; exact,
            // m values are already f16-rounded)
            __builtin_amdgcn_s_waitcnt(0xC07F);  // lgkmcnt(0): m_s visible in-wave
            if (tid < 32) {
                uint_t pk = (uint_t)f2h(m_s[2 * tid])
                          | ((uint_t)f2h(m_s[2 * tid + 1]) << 16);
                m2_s[tid] = pk;
            }
        }
        __syncthreads();

        // ---- broadcast packed m into persistent registers ----
        {
            const uint4* mg = (const uint4*)m2_s;
#pragma unroll
            for (int p = 0; p < 8; ++p) {
                uint4 v = mg[p];
                mreg2u[p * 4 + 0] = v.x;
                mreg2u[p * 4 + 1] = v.y;
                mreg2u[p * 4 + 2] = v.z;
                mreg2u[p * 4 + 3] = v.w;
            }
        }
    }
}

// ---------------- K5: parallel loss (reads f16 mailbox) ----------------
__global__ __launch_bounds__(256) void loss_kernel(
    const us_t* __restrict__ mhb, const us_t* __restrict__ decwY,
    const float* __restrict__ decb, const int* __restrict__ x0,
    float* __restrict__ out) {
    __shared__ __align__(16) us_t dw[16384];   // [mm][lane][k<4] bf16
    const int tid = threadIdx.x;
    {
        const uint4* g4 = (const uint4*)decwY;
        uint4* l4 = (uint4*)dw;
        for (int k = tid; k < 2048; k += 256) l4[k] = g4[k];
    }
    __syncthreads();
    const int lane = tid & 63, wv = tid >> 6;
    const uint2* dwu2 = (const uint2*)dw;
    float b0 = decb[lane], b1 = decb[lane + 64];
    float b2 = decb[lane + 128], b3 = decb[lane + 192];
    for (int r = 0; r < 8; ++r) {
        int row = blockIdx.x * 32 + wv * 8 + r;
        float mL = h2f(mhb[row * 64 + lane]);
        float l0 = b0, l1 = b1, l2 = b2, l3 = b3;
#pragma unroll
        for (int mm = 0; mm < 64; ++mm) {
            float mv = __shfl(mL, mm, 64);
            uint2 q = dwu2[mm * 64 + lane];
            l0 += mv * bflo(q.x);
            l1 += mv * bfhi(q.x);
            l2 += mv * bflo(q.y);
            l3 += mv * bfhi(q.y);
        }
        float mx = fmaxf(fmaxf(l0, l1), fmaxf(l2, l3));
#pragma unroll
        for (int o = 32; o > 0; o >>= 1) mx = fmaxf(mx, __shfl_xor(mx, o, 64));
        float se = __expf(l0 - mx) + __expf(l1 - mx) + __expf(l2 - mx) + __expf(l3 - mx);
#pragma unroll
        for (int o = 32; o > 0; o >>= 1) se += __shfl_xor(se, o, 64);
        float lse = mx + __logf(se);
        int t = row >> 4, bb = row & 15;
        int y = x0[bb * 2048 + t];
        int hi = y >> 6;
        float cand = hi == 0 ? l0 : (hi == 1 ? l1 : (hi == 2 ? l2 : l3));
        float ly = __shfl(cand, y & 63, 64);
        if (lane == 0) out[row] = (lse - ly) * 1.4426950408889634f;
    }
}

extern "C" void kernel_launch(void* const* d_in, const int* in_sizes, int n_in,
                              void* d_out, int out_size, void* d_ws, size_t ws_size,
                              hipStream_t stream) {
    const int*   x0    = (const int*)d_in[0];
    const float* emb   = (const float*)d_in[1];
    const float* Wencw = (const float*)d_in[2];
    const float* Wencb = (const float*)d_in[3];
    const float* Wdecw = (const float*)d_in[4];
    const float* Wdecb = (const float*)d_in[5];
    const float* bencw = (const float*)d_in[6];
    const float* bencb = (const float*)d_in[7];
    const float* bdecw = (const float*)d_in[8];
    const float* bdecb = (const float*)d_in[9];
    const float* decw  = (const float*)d_in[10];
    const float* decb  = (const float*)d_in[11];
    float* out = (float*)d_out;

    char* ws = (char*)d_ws;
    us_t*  WdG   = (us_t*)(ws);                 //       0 .. 524288
    us_t*  decwY = (us_t*)(ws + 524288);        //  524288 .. 557056
    us_t*  EWmG  = (us_t*)(ws + 557056);        //  557056 .. 573440 (16 KB)
    float* T     = (float*)(ws + 573440);       //  573440 .. 8962048 (8 MB)
    u64_t* mhb   = (u64_t*)T;                   //  alias: T dead after build_P
    float* P     = (float*)(ws + 8962048);      // 8962048 .. 25739264 (16 MB)

    static const int kRecurLds = 157632;
    (void)hipFuncSetAttribute((const void*)recur,
                              hipFuncAttributeMaxDynamicSharedMemorySize,
                              kRecurLds);

    cvt_kernel<<<1120, 256, 0, stream>>>(Wdecw, decw, Wencw, bencw,
                                         WdG, decwY, EWmG);
    build_T<<<16384, 128, 0, stream>>>(emb, Wencw, bencw, T);
    build_P<<<32768, 128, 0, stream>>>(T, x0, Wencb, bencb, P);
    // poison the mailbox AFTER build_P (mhb aliases T), BEFORE recur
    (void)hipMemsetAsync(mhb, 0xAA, 4194304, stream);
    recur<<<64, 512, kRecurLds, stream>>>(bdecw, bdecb, Wdecb, WdG, EWmG,
                                          P, mhb);
    loss_kernel<<<1024, 256, 0, stream>>>((const us_t*)mhb, decwY, decb, x0, out);
}

// Round 13
// 3722.043 us; speedup vs baseline: 2.5497x; 1.0650x over previous
//
#include <hip/hip_runtime.h>
#include <hip/hip_bf16.h>
#include <hip/hip_fp16.h>

// Hypernetwork RNN scan. B=16, N=2048, M=H=64, L*E=1024, Cout=256.
// Round 13: h-slice decomposition. R12's step is 55% exchange stall because
// i-slicing forces publish AFTER the full B+C reduction and nothing overlaps
// the LLC RTT. Slicing by h instead: WG s owns Wd rows h in [16s,16s+16) x
// all i; the exchanged quantity is the f32 PARTIAL row r_s[i] (ready ~200cyc
// after sync1), and the local terms (Wdb*m, bdec*hb) compute on idle waves
// UNDER the in-flight RTT. Every WG assembles identical full m locally
// (fixed-order f32 partial sum -> bit-identical across WGs). Exchange:
// tagged-u64 (tag|f32bits), ping-pong parity slots (deadlock-free: producer
// reuses a slot for t+2 only after all peers consumed t), 3 polling waves.
//   K1 cvt: Wd->f16 h-slice layout; enc m-rows->f16; dec_w->bf16 (loss)
//   K2 build_T (f32, 8 MB), K3 build_P (f32, 16 MB)
//   K4 recur: 64 WGs = 16 batches x 4 h-slices; Wd in VGPRs (R12 win)
//   K5 loss:  parallel logits/LSE/NLL over the f16 m history (s=0 writes)

typedef unsigned int uint_t;
typedef unsigned short us_t;
typedef unsigned long long u64_t;
typedef _Float16 h2_t __attribute__((ext_vector_type(2)));

__device__ __forceinline__ us_t f2bf(float f) {
    uint_t u = __float_as_uint(f);
    uint_t r = u + 0x7fffu + ((u >> 16) & 1u);   // RNE
    return (us_t)(r >> 16);
}
__device__ __forceinline__ float bflo(uint_t u) { return __uint_as_float(u << 16); }
__device__ __forceinline__ float bfhi(uint_t u) { return __uint_as_float(u & 0xffff0000u); }

__device__ __forceinline__ us_t f2h(float f) {
    __half h = __float2half(f);                  // RNE
    return *reinterpret_cast<us_t*>(&h);
}
__device__ __forceinline__ float h2f(us_t s) {
    __half h = *reinterpret_cast<__half*>(&s);
    return __half2float(h);
}
__device__ __forceinline__ h2_t u2h2(uint_t u) {
    union { uint_t u; h2_t h; } x; x.u = u; return x.h;
}

#if __has_builtin(__builtin_amdgcn_fdot2)
__device__ __forceinline__ float dot2f(uint_t a, uint_t b, float c) {
    return __builtin_amdgcn_fdot2(u2h2(a), u2h2(b), c, false);
}
#else
__device__ __forceinline__ float dot2f(uint_t a, uint_t b, float c) {
    h2_t x = u2h2(a), y = u2h2(b);
    return c + (float)x.x * (float)y.x + (float)x.y * (float)y.y;
}
#endif

#define DOT4(q, base, acc)                                              \
    acc = dot2f(q.x, mreg2u[(base) + 0], acc);                          \
    acc = dot2f(q.y, mreg2u[(base) + 1], acc);                          \
    acc = dot2f(q.z, mreg2u[(base) + 2], acc);                          \
    acc = dot2f(q.w, mreg2u[(base) + 3], acc);

// ---------------- K1: convert/swizzle weights ----------------
// WdG  [s<4][jp<8][o<1024][k<8] f16: h = s*16 + (o>>6), i = o&63, j = jp*8+k
//      val = Wd[h][i*64 + j]   (h-slice layout; uint4 at jp*1024+o lane-contig)
// decwY [mm<64][lane<64][k<4] bf16: val = decw[mm*256 + k*64 + lane]
// EWmG [jp<8][h2<128][k<8] f16: val = enc_m_row(j=jp*8+k, h2)
__global__ void cvt_kernel(const float* __restrict__ Wdecw,
                           const float* __restrict__ decw,
                           const float* __restrict__ Wencw,
                           const float* __restrict__ bencw,
                           us_t* __restrict__ WdG, us_t* __restrict__ decwY,
                           us_t* __restrict__ EWmG) {
    int o = blockIdx.x * 256 + threadIdx.x;
    if (o < 262144) {
        int s = o >> 16;
        int idx = o & 65535;
        int k = idx & 7;
        int oo = (idx >> 3) & 1023;
        int jp = idx >> 13;
        int h = s * 16 + (oo >> 6);
        int i = oo & 63;
        int j = jp * 8 + k;
        WdG[o] = f2h(Wdecw[h * 4096 + i * 64 + j]);
    } else if (o < 278528) {
        int oo = o - 262144;
        int k = oo & 3, lane = (oo >> 2) & 63, mm = oo >> 8;
        decwY[oo] = f2bf(decw[mm * 256 + k * 64 + lane]);
    } else if (o < 286720) {
        int oo = o - 278528;
        int kk = oo & 7, h2 = (oo >> 3) & 127, jp = oo >> 10;
        int j = jp * 8 + kk;
        float v = (h2 < 64) ? Wencw[j * 64 + h2] : bencw[j * 64 + (h2 - 64)];
        EWmG[oo] = f2h(v);
    }
}

// ---------------- K2: token contribution table ----------------
__global__ void build_T(const float* __restrict__ emb, const float* __restrict__ Wencw,
                        const float* __restrict__ bencw, float* __restrict__ T) {
    int l = blockIdx.x >> 8, v = blockIdx.x & 255, h2 = threadIdx.x;  // h2 < 128
    float acc = 0.f;
#pragma unroll
    for (int e = 0; e < 16; ++e) {
        int d = 64 + l * 16 + e;
        float w = (h2 < 64) ? Wencw[d * 64 + h2] : bencw[d * 64 + (h2 - 64)];
        acc += emb[v * 16 + e] * w;
    }
    T[blockIdx.x * 128 + h2] = acc;
}

// ---------------- K3: window precompute P (f32) ----------------
__global__ void build_P(const float* __restrict__ T, const int* __restrict__ x0,
                        const float* __restrict__ Wencb, const float* __restrict__ bencb,
                        float* __restrict__ P) {
    int t = blockIdx.x >> 4, b = blockIdx.x & 15, h2 = threadIdx.x;  // h2 < 128
    float acc = (h2 < 64) ? Wencb[h2] : bencb[h2 - 64];
    for (int l = 0; l < 64; ++l) {
        int p = t + l;
        int v = (p < 64) ? 0 : x0[b * 2048 + (p - 64)];
        acc += T[(l * 256 + v) * 128 + h2];
    }
    P[blockIdx.x * 128 + h2] = acc;
}

// ---------------- K4: sequential recurrence (h-slice) ----------------
// grid 64: b = blk&15, s = blk>>4. ~40 KB live LDS + pad to 157632 -> 1 WG/CU.
__global__ __launch_bounds__(512, 2) void recur(
    const float* __restrict__ bdecw, const float* __restrict__ bdecb,
    const float* __restrict__ Wdecb, const us_t* __restrict__ WdG,
    const us_t* __restrict__ EWmG, const float* __restrict__ P,
    uint_t* __restrict__ mh32, u64_t* __restrict__ pxb) {
    const int b = blockIdx.x & 15, s = blockIdx.x >> 4;
    const int tid = threadIdx.x;

    extern __shared__ char smem[];
    us_t*   EWm2   = (us_t*)(smem);                // 16384 [jp][h2][8] f16
    uint_t* wdbt2  = (uint_t*)(smem + 16384);      // 8192 [jj<32][i<64]: (Wdb[i][2jj],Wdb[i][2jj+1]) f16
    uint_t* bdec2  = (uint_t*)(smem + 24576);      // 8192 [hh<32][i<64]: (bdec[2hh][i],bdec[2hh+1][i]) f16
    float*  V_s    = (float*)(smem + 32768);       // 4160 [hl<16][i<64] stride 65
    float*  rp4_s  = (float*)(smem + 36928);       // 1024 [p<4][i]
    float*  wdbm2_s= (float*)(smem + 37952);       // 512  [q<2][i]
    float*  hbb2_s = (float*)(smem + 38464);       // 512  [q<2][i]
    float*  hw_s   = (float*)(smem + 38976);       // 256
    uint_t* hb2_s  = (uint_t*)(smem + 39232);      // 128 packed f16 hb pairs
    uint_t* m2_s   = (uint_t*)(smem + 39360);      // 128 packed f16 m pairs
    float*  bias_s = (float*)(smem + 39488);       // 256
    // live total 39744; pad to 157632 at launch (1 WG/CU)

    // ---- init: Wd h-slice -> registers (rows o=tid, o=tid+512) ----
    uint4 wreg[16];
    {
        const uint4* g4 = (const uint4*)WdG + s * 8192;
#pragma unroll
        for (int jp = 0; jp < 8; ++jp) {
            wreg[jp]     = g4[jp * 1024 + tid];
            wreg[8 + jp] = g4[jp * 1024 + tid + 512];
        }
    }
    {
        const uint4* g4 = (const uint4*)EWmG;
        uint4* l4 = (uint4*)EWm2;
        for (int k = tid; k < 1024; k += 512) l4[k] = g4[k];
    }
    for (int k = tid; k < 2048; k += 512) {
        int jj = k >> 6, i = k & 63;
        wdbt2[k] = (uint_t)f2h(Wdecb[i * 64 + 2 * jj])
                 | ((uint_t)f2h(Wdecb[i * 64 + 2 * jj + 1]) << 16);
        bdec2[k] = (uint_t)f2h(bdecw[(2 * jj) * 64 + i])
                 | ((uint_t)f2h(bdecw[(2 * jj + 1) * 64 + i]) << 16);
    }
    if (tid < 64) bias_s[tid] = bdecb[tid];
    if (tid < 32) m2_s[tid] = 0u;
    __syncthreads();

    // persistent m as 32 packed half2 regs; COMPILE-TIME indexing only
    // (Round-3 lesson: any runtime index demotes the array to scratch).
    uint_t mreg2u[32];
#pragma unroll
    for (int j = 0; j < 32; ++j) mreg2u[j] = 0u;

    float preg = 0.f;
    if (tid < 128) preg = P[b * 128 + tid];  // t = 0

    const uint4* EW4 = (const uint4*)EWm2;
    const int hl = tid >> 6, iA = tid & 63;
    const int w = tid >> 6;   // wave index

    for (int t = 0; t < 2048; ++t) {
        // ---- phase A: P prefetch; V slice (Wd regs); henc; hb pack ----
        float pnext = 0.f;
        int tp = (t < 2047) ? (t + 1) : 2047;
        if (tid < 128) pnext = P[(tp * 16 + b) * 128 + tid];

        float a0 = 0.f, a1 = 0.f;
#pragma unroll
        for (int jp = 0; jp < 8; ++jp) {
            uint4 q0 = wreg[jp];
            uint4 q1 = wreg[8 + jp];
            DOT4(q0, jp * 4, a0);
            DOT4(q1, jp * 4, a1);
        }
        V_s[hl * 65 + iA] = a0;        // h_local = hl
        V_s[(hl + 8) * 65 + iA] = a1;  // h_local = hl + 8

        if (tid < 128) {
            float acc = preg;
#pragma unroll
            for (int jp = 0; jp < 8; ++jp) {
                uint4 e = EW4[jp * 128 + tid];
                DOT4(e, jp * 4, acc);
            }
            float sg = 1.f / (1.f + __expf(-acc));
            if (tid < 64) {
                hw_s[tid] = sg;
            } else {
                int l = tid - 64;            // lane within wave 1
                float vlo = __shfl(sg, (l & 31) * 2, 64);
                float vhi = __shfl(sg, (l & 31) * 2 + 1, 64);
                if (l < 32)
                    hb2_s[l] = (uint_t)f2h(vlo) | ((uint_t)f2h(vhi) << 16);
            }
        }
        preg = pnext;
        __syncthreads();   // sync1

        // ---- exchange phase ----
        u64_t* slotb = pxb + (u64_t)(((t & 1) * 16 + b) * 4) * 64;
        const uint_t tg = (uint_t)(t + 1);

        if (tid < 64) {
            // wave 0: own partial r_s[i] over the 16 owned h, then publish
            float r0 = 0.f, r1 = 0.f;
#pragma unroll
            for (int hh = 0; hh < 8; ++hh) {
                r0 += hw_s[s * 16 + 2 * hh]     * V_s[(2 * hh) * 65 + tid];
                r1 += hw_s[s * 16 + 2 * hh + 1] * V_s[(2 * hh + 1) * 65 + tid];
            }
            float rs = r0 + r1;
            rp4_s[s * 64 + tid] = rs;
            u64_t pay = ((u64_t)tg << 32) | (u64_t)__float_as_uint(rs);
            __hip_atomic_store(slotb + s * 64 + tid, pay,
                               __ATOMIC_RELAXED, __HIP_MEMORY_SCOPE_AGENT);
        }

        if (w < 3) {
            // polling waves 0,1,2: one peer slot each; detection IS payload
            int p = w + (w >= s ? 1 : 0);
            int lane = tid & 63;
            const u64_t* src = slotb + p * 64 + lane;
            u64_t v;
            for (;;) {
                v = __hip_atomic_load(src, __ATOMIC_RELAXED,
                                      __HIP_MEMORY_SCOPE_AGENT);
                if (__ballot((uint_t)(v >> 32) == tg) == ~0ull) break;
                __builtin_amdgcn_s_sleep(1);
            }
            rp4_s[p * 64 + lane] = __uint_as_float((uint_t)v);
        } else if (w < 5) {
            // worker waves 3,4: local terms, overlapped with the RTT
            int i = tid & 63;
            float wm = 0.f, hbv = 0.f;
            if (w == 3) {
#pragma unroll
                for (int jj = 0; jj < 16; ++jj) {
                    wm  = dot2f(wdbt2[jj * 64 + i], mreg2u[jj], wm);
                    hbv = dot2f(bdec2[jj * 64 + i], hb2_s[jj], hbv);
                }
                wdbm2_s[i] = wm;
                hbb2_s[i] = hbv;
            } else {
#pragma unroll
                for (int jj = 0; jj < 16; ++jj) {
                    wm  = dot2f(wdbt2[(16 + jj) * 64 + i], mreg2u[16 + jj], wm);
                    hbv = dot2f(bdec2[(16 + jj) * 64 + i], hb2_s[16 + jj], hbv);
                }
                wdbm2_s[64 + i] = wm;
                hbb2_s[64 + i] = hbv;
            }
        }
        __syncthreads();   // sync2

        // ---- final: assemble identical full m locally (fixed order) ----
        if (tid < 64) {
            float r = ((rp4_s[tid] + rp4_s[64 + tid])
                     + (rp4_s[128 + tid] + rp4_s[192 + tid]))
                    + (wdbm2_s[tid] + wdbm2_s[64 + tid])
                    + (hbb2_s[tid] + hbb2_s[64 + tid])
                    + bias_s[tid];
            float nm = 1.f / (1.f + __expf(-r));
            us_t nh = f2h(nm);                  // f16 round: all WGs agree
            uint_t nhu = (uint_t)nh;
            uint_t lo = (uint_t)__shfl((int)nhu, (tid & 31) * 2, 64);
            uint_t hi = (uint_t)__shfl((int)nhu, (tid & 31) * 2 + 1, 64);
            if (tid < 32) {
                uint_t pk = lo | (hi << 16);
                m2_s[tid] = pk;
                if (s == 0) mh32[(t * 16 + b) * 32 + tid] = pk;  // history
            }
        }
        __syncthreads();   // sync3

        // ---- reload packed m into persistent registers ----
        {
            const uint4* mg = (const uint4*)m2_s;
#pragma unroll
            for (int p = 0; p < 8; ++p) {
                uint4 v = mg[p];
                mreg2u[p * 4 + 0] = v.x;
                mreg2u[p * 4 + 1] = v.y;
                mreg2u[p * 4 + 2] = v.z;
                mreg2u[p * 4 + 3] = v.w;
            }
        }
    }
}

// ---------------- K5: parallel loss (reads f16 m history) ----------------
__global__ __launch_bounds__(256) void loss_kernel(
    const us_t* __restrict__ mhb, const us_t* __restrict__ decwY,
    const float* __restrict__ decb, const int* __restrict__ x0,
    float* __restrict__ out) {
    __shared__ __align__(16) us_t dw[16384];   // [mm][lane][k<4] bf16
    const int tid = threadIdx.x;
    {
        const uint4* g4 = (const uint4*)decwY;
        uint4* l4 = (uint4*)dw;
        for (int k = tid; k < 2048; k += 256) l4[k] = g4[k];
    }
    __syncthreads();
    const int lane = tid & 63, wv = tid >> 6;
    const uint2* dwu2 = (const uint2*)dw;
    float b0 = decb[lane], b1 = decb[lane + 64];
    float b2 = decb[lane + 128], b3 = decb[lane + 192];
    for (int r = 0; r < 8; ++r) {
        int row = blockIdx.x * 32 + wv * 8 + r;
        float mL = h2f(mhb[row * 64 + lane]);
        float l0 = b0, l1 = b1, l2 = b2, l3 = b3;
#pragma unroll
        for (int mm = 0; mm < 64; ++mm) {
            float mv = __shfl(mL, mm, 64);
            uint2 q = dwu2[mm * 64 + lane];
            l0 += mv * bflo(q.x);
            l1 += mv * bfhi(q.x);
            l2 += mv * bflo(q.y);
            l3 += mv * bfhi(q.y);
        }
        float mx = fmaxf(fmaxf(l0, l1), fmaxf(l2, l3));
#pragma unroll
        for (int o = 32; o > 0; o >>= 1) mx = fmaxf(mx, __shfl_xor(mx, o, 64));
        float se = __expf(l0 - mx) + __expf(l1 - mx) + __expf(l2 - mx) + __expf(l3 - mx);
#pragma unroll
        for (int o = 32; o > 0; o >>= 1) se += __shfl_xor(se, o, 64);
        float lse = mx + __logf(se);
        int t = row >> 4, bb = row & 15;
        int y = x0[bb * 2048 + t];
        int hi = y >> 6;
        float cand = hi == 0 ? l0 : (hi == 1 ? l1 : (hi == 2 ? l2 : l3));
        float ly = __shfl(cand, y & 63, 64);
        if (lane == 0) out[row] = (lse - ly) * 1.4426950408889634f;
    }
}

extern "C" void kernel_launch(void* const* d_in, const int* in_sizes, int n_in,
                              void* d_out, int out_size, void* d_ws, size_t ws_size,
                              hipStream_t stream) {
    const int*   x0    = (const int*)d_in[0];
    const float* emb   = (const float*)d_in[1];
    const float* Wencw = (const float*)d_in[2];
    const float* Wencb = (const float*)d_in[3];
    const float* Wdecw = (const float*)d_in[4];
    const float* Wdecb = (const float*)d_in[5];
    const float* bencw = (const float*)d_in[6];
    const float* bencb = (const float*)d_in[7];
    const float* bdecw = (const float*)d_in[8];
    const float* bdecb = (const float*)d_in[9];
    const float* decw  = (const float*)d_in[10];
    const float* decb  = (const float*)d_in[11];
    float* out = (float*)d_out;

    char* ws = (char*)d_ws;
    us_t*   WdG   = (us_t*)(ws);                 //       0 .. 524288
    us_t*   decwY = (us_t*)(ws + 524288);        //  524288 .. 557056
    us_t*   EWmG  = (us_t*)(ws + 557056);        //  557056 .. 573440 (16 KB)
    u64_t*  pxb   = (u64_t*)(ws + 573440);       //  573440 .. 638976 (64 KB, 2-parity)
    float*  T     = (float*)(ws + 638976);       //  638976 .. 9027584 (8 MB)
    uint_t* mh32  = (uint_t*)T;                  //  alias: T dead after build_P (4 MB)
    float*  P     = (float*)(ws + 9027584);      // 9027584 .. 25804800 (16 MB)

    static const int kRecurLds = 157632;
    (void)hipFuncSetAttribute((const void*)recur,
                              hipFuncAttributeMaxDynamicSharedMemorySize,
                              kRecurLds);

    cvt_kernel<<<1120, 256, 0, stream>>>(Wdecw, decw, Wencw, bencw,
                                         WdG, decwY, EWmG);
    build_T<<<16384, 128, 0, stream>>>(emb, Wencw, bencw, T);
    build_P<<<32768, 128, 0, stream>>>(T, x0, Wencb, bencb, P);
    // zero the tag mailbox (tag 0 never matches t+1 >= 1)
    (void)hipMemsetAsync(pxb, 0, 65536, stream);
    recur<<<64, 512, kRecurLds, stream>>>(bdecw, bdecb, Wdecb, WdG, EWmG,
                                          P, mh32, pxb);
    loss_kernel<<<1024, 256, 0, stream>>>((const us_t*)mh32, decwY, decb, x0, out);
}